// Round 9
// baseline (818.110 us; speedup 1.0000x reference)
//
#include <hip/hip_runtime.h>
#include <cstdint>
#include <cstddef>

#define INDIM 512
#define HIDD  256
#define OUTD  32
#define PCH   4096   // edges per partition block

typedef __attribute__((ext_vector_type(4))) float f32x4;
typedef __attribute__((ext_vector_type(8))) short bf16x8;

// ---- bf16 <-> f32 helpers ----
static inline __device__ float b2f(unsigned short u) {
  union { float f; unsigned int i; } v; v.i = ((unsigned int)u) << 16; return v.f;
}
static inline __device__ unsigned short f2b(float f) {
  union { float f; unsigned int i; } v; v.f = f;
  unsigned int x = v.i;
  x += 0x7fffu + ((x >> 16) & 1u);   // round-to-nearest-even
  return (unsigned short)(x >> 16);
}

// edge weight: exp(sigmoid(x)) — SAME formula in both agg kernels
static inline __device__ float edgew(float x) {
  float al = 1.f / (1.f + __expf(-x));
  return __expf(al);
}

// async global->LDS, 16B per lane. LDS dest = wave-uniform base + lane*16.
static __device__ __forceinline__ void gld16(const unsigned short* g, unsigned short* l) {
  __builtin_amdgcn_global_load_lds(
      (const __attribute__((address_space(1))) void*)g,
      (__attribute__((address_space(3))) void*)l, 16, 0, 0);
}

// ---- runtime dtype probe ----
__global__ __launch_bounds__(256) void probe_kernel(
    const unsigned int* __restrict__ feat, const unsigned int* __restrict__ eidx,
    int* __restrict__ flags)
{
  int t = threadIdx.x;
  __shared__ int cnt, oddnz;
  if (t == 0) { cnt = 0; oddnz = 0; }
  __syncthreads();
  unsigned int w = feat[t];
  unsigned short lo = (unsigned short)(w & 0xFFFFu);
  int e = (lo >> 7) & 0xFF;
  int plausible = ((lo & 0x7FFF) == 0) || (e >= 0x60 && e <= 0x9F);
  atomicAdd(&cnt, plausible);
  if (t & 1) { if (eidx[t] != 0u) atomicAdd(&oddnz, 1); }
  __syncthreads();
  if (t == 0) { flags[0] = (cnt >= 192) ? 1 : 0; flags[1] = (oddnz == 0) ? 1 : 0; }
}

// ---- P1: node degree histogram + coarse slab histogram ----
__global__ __launch_bounds__(256) void p1_kernel(
    const unsigned int* __restrict__ eidx, int* __restrict__ deg,
    int* __restrict__ slabCount, int E, int shift, int nslab,
    const int* __restrict__ flags)
{
  __shared__ int hist[64];
  int t = threadIdx.x;
  if (t < 64) hist[t] = 0;
  __syncthreads();
  int e = blockIdx.x * 256 + t;
  if (e < E) {
    int d = flags[1] ? (int)eidx[2 * ((size_t)E + e)] : (int)eidx[(size_t)E + e];
    atomicAdd(&deg[d], 1);
    atomicAdd(&hist[d >> shift], 1);
  }
  __syncthreads();
  if (t < nslab && hist[t]) atomicAdd(&slabCount[t], hist[t]);
}

// ---- slab exclusive scan (single wave, nslab <= 64) ----
__global__ __launch_bounds__(64) void slabscan_kernel(
    const int* __restrict__ slabCount, int* __restrict__ slabOff,
    int* __restrict__ slabCur, int nslab)
{
  int t = threadIdx.x;
  int v = (t < nslab) ? slabCount[t] : 0;
  int inc = v;
#pragma unroll
  for (int o = 1; o < 64; o <<= 1) {
    int u = __shfl_up(inc, o);
    if (t >= o) inc += u;
  }
  int exc = inc - v;
  if (t < nslab) { slabOff[t] = exc; slabCur[t] = exc; }
  if (t == 63) slabOff[nslab] = inc;   // total = E (lanes beyond nslab add 0)
}

// ---- P2: partition (src,dst) pairs into slab-contiguous regions ----
__global__ __launch_bounds__(256) void part_kernel(
    const unsigned int* __restrict__ eidx, int* __restrict__ slabCur,
    uint2* __restrict__ part, int E, int shift, int nslab,
    const int* __restrict__ flags)
{
  __shared__ int hist[64], base[64];
  int t = threadIdx.x;
  int e0 = blockIdx.x * PCH;
  const int i64 = flags[1];
  if (t < 64) hist[t] = 0;
  __syncthreads();
  for (int i = t; i < PCH; i += 256) {
    int e = e0 + i; if (e >= E) break;
    int d = i64 ? (int)eidx[2 * ((size_t)E + e)] : (int)eidx[(size_t)E + e];
    atomicAdd(&hist[d >> shift], 1);
  }
  __syncthreads();
  if (t < nslab) {
    base[t] = hist[t] ? atomicAdd(&slabCur[t], hist[t]) : 0;
    hist[t] = 0;   // reuse as local cursor
  }
  __syncthreads();
  for (int i = t; i < PCH; i += 256) {
    int e = e0 + i; if (e >= E) break;
    int s, d;
    if (i64) { s = (int)eidx[2 * (size_t)e]; d = (int)eidx[2 * ((size_t)E + e)]; }
    else     { s = (int)eidx[e];             d = (int)eidx[(size_t)E + e]; }
    int sl = d >> shift;
    int r = atomicAdd(&hist[sl], 1);
    part[(size_t)base[sl] + r] = make_uint2((unsigned)s, (unsigned)d);
  }
}

// ---- P3: fill srcP slab-by-slab, slab%8 pinned to blockIdx%8 (XCD locality) ----
__global__ __launch_bounds__(256) void fill2_kernel(
    const uint2* __restrict__ part, const int* __restrict__ slabOff,
    int* __restrict__ cur, int* __restrict__ srcP, int nslab)
{
  int xcd = blockIdx.x & 7, j = blockIdx.x >> 3;   // 64 sibling blocks per xcd
  int t = threadIdx.x;
  for (int sl = xcd; sl < nslab; sl += 8) {
    int s0 = slabOff[sl], s1 = slabOff[sl + 1];
    for (int i = s0 + j * 256 + t; i < s1; i += 64 * 256) {
      uint2 p = part[i];
      int pos = atomicAdd(&cur[p.y], 1);
      srcP[pos] = (int)p.x;
    }
  }
}

static inline __device__ float ldadapt(const void* p, size_t i, int isbf) {
  return isbf ? b2f(((const unsigned short*)p)[i]) : ((const float*)p)[i];
}

// ---- weight prep: W1b, W1tb, W2f, W2b64 ([256][64] bf16, zero-padded K), att ----
__global__ __launch_bounds__(256) void prep_weights(
    const void* __restrict__ W1, const void* __restrict__ W2,
    const void* __restrict__ aS, const void* __restrict__ aD,
    unsigned short* __restrict__ W1b, unsigned short* __restrict__ W1tb,
    float* __restrict__ W2f, unsigned short* __restrict__ W2b64,
    float* __restrict__ atS, float* __restrict__ atD,
    const int* __restrict__ flags)
{
  const int fb = flags[0];
  int i = blockIdx.x * 256 + threadIdx.x;
  if (i < INDIM * HIDD) {               // W1: [512][256]
    int r = i >> 8, c = i & 255;
    float w0 = ldadapt(W1, i, fb);
    unsigned short wb = f2b(w0);
    W1b[i] = wb;                        // Bt for h4: [512 rows][256 k]
    W1tb[c * INDIM + r] = wb;           // Bt for xp1: [256 rows][512 k]
  }
  if (i < HIDD * OUTD) {                // W2: [256][32]
    int r = i >> 5, c = i & 31;
    float w0 = ldadapt(W2, i, fb);
    W2f[i] = w0;
    W2b64[r * 64 + c] = f2b(w0);        // Bt for h3: [256 rows][64 k], upper 32 zero
    W2b64[r * 64 + 32 + c] = 0;
  }
  if (i < HIDD) { atS[i] = ldadapt(aS, i, fb); atD[i] = ldadapt(aD, i, fb); }
}

// =====================================================================
// m97-structure MFMA NT GEMM: C[M][Nn] = A[M][K] @ Bt[Nn][K]^T.
// AMODE:   0 = A bf16 ws buffer (gld16, rows to M_pad readable)
//          1 = A external input: fb ? bf16 gld16 : f32 reg-stage+convert (row-clamped)
// OUTMODE: 0 = bf16 to Cb; 1 = adaptive (flags[0]) to Out+outOff
// EPI:     0 = none; 1 = ELU before store
// =====================================================================
template<int AMODE, int OUTMODE, int EPI>
__global__ __launch_bounds__(256) void gemm_nt2(
    const void* __restrict__ Av, const unsigned short* __restrict__ Bt,
    unsigned short* __restrict__ Cb, void* __restrict__ Out, size_t outOff,
    const int* __restrict__ flags, int M, int Nn, int K)
{
  __shared__ unsigned short Als[128 * 64];
  __shared__ unsigned short Bls[128 * 64];
  const int tid = threadIdx.x, lane = tid & 63, wid = tid >> 6;
  const int wr = wid >> 1, wc = wid & 1;
  const int rowBase = blockIdx.y * 128, colBase = blockIdx.x * 128;
  const int fb = flags[0];

  const int srow = (lane >> 3), sg = lane & 7;

  f32x4 acc[4][4] = {};

  for (int kt = 0; kt < K; kt += 64) {
    if (AMODE == 1 && !fb) {
      const float* Af = (const float*)Av;
#pragma unroll
      for (int i = 0; i < 4; ++i) {
        int row = wid * 32 + i * 8 + srow;
        int gr = rowBase + row; if (gr > M - 1) gr = M - 1;
        const float* sp = Af + (size_t)gr * K + kt + sg * 8;
        float4 lo = *(const float4*)sp;
        float4 hi = *(const float4*)(sp + 4);
        union { unsigned short us[8]; int4 v; } cv;
        cv.us[0] = f2b(lo.x); cv.us[1] = f2b(lo.y); cv.us[2] = f2b(lo.z); cv.us[3] = f2b(lo.w);
        cv.us[4] = f2b(hi.x); cv.us[5] = f2b(hi.y); cv.us[6] = f2b(hi.z); cv.us[7] = f2b(hi.w);
        *(int4*)(Als + (wid * 4 + i) * 512 + lane * 8) = cv.v;
      }
    } else {
      const unsigned short* Ab = (const unsigned short*)Av;
#pragma unroll
      for (int i = 0; i < 4; ++i) {
        int row = wid * 32 + i * 8 + srow;
        int gr = rowBase + row;
        if (AMODE == 1 && gr > M - 1) gr = M - 1;   // external input: clamp
        gld16(Ab + (size_t)gr * K + kt + sg * 8, Als + (wid * 4 + i) * 512);
      }
    }
#pragma unroll
    for (int i = 0; i < 4; ++i) {
      int row = wid * 32 + i * 8 + srow;
      gld16(Bt + (size_t)(colBase + row) * K + kt + sg * 8, Bls + (wid * 4 + i) * 512);
    }
    __syncthreads();

    bf16x8 af[4], bfr[4];
#pragma unroll
    for (int ks = 0; ks < 2; ++ks) {
      int g = ks * 4 + (lane >> 4);
#pragma unroll
      for (int mi = 0; mi < 4; ++mi) {
        int row = wr * 64 + mi * 16 + (lane & 15);
        af[mi] = *(const bf16x8*)(Als + row * 64 + g * 8);
      }
#pragma unroll
      for (int ni = 0; ni < 4; ++ni) {
        int row = wc * 64 + ni * 16 + (lane & 15);
        bfr[ni] = *(const bf16x8*)(Bls + row * 64 + g * 8);
      }
#pragma unroll
      for (int mi = 0; mi < 4; ++mi)
#pragma unroll
        for (int ni = 0; ni < 4; ++ni)
          acc[mi][ni] = __builtin_amdgcn_mfma_f32_16x16x32_bf16(af[mi], bfr[ni], acc[mi][ni], 0, 0, 0);
    }
    __syncthreads();
  }

  // C/D: col = lane&15, row = (lane>>4)*4 + reg
#pragma unroll
  for (int mi = 0; mi < 4; ++mi) {
    int r0 = rowBase + wr * 64 + mi * 16 + (lane >> 4) * 4;
#pragma unroll
    for (int ni = 0; ni < 4; ++ni) {
      int c = colBase + wc * 64 + ni * 16 + (lane & 15);
#pragma unroll
      for (int v = 0; v < 4; ++v) {
        int r = r0 + v;
        if (r < M) {
          size_t idx = (size_t)r * Nn + c;
          float x = acc[mi][ni][v];
          if (EPI) x = x > 0.f ? x : expm1f(x);
          if (OUTMODE == 0) Cb[idx] = f2b(x);
          else {
            if (fb) ((unsigned short*)Out)[outOff + idx] = f2b(x);
            else    ((float*)Out)[outOff + idx] = x;
          }
        }
      }
    }
  }
}

// ---- a_src / a_dst: one wave per node, dot(xp1_row, att); P is bf16 ----
__global__ __launch_bounds__(256) void rowdots(
    const unsigned short* __restrict__ P, const float* __restrict__ atS,
    const float* __restrict__ atD,
    float* __restrict__ asrc, float* __restrict__ adst, int N)
{
  int wave = threadIdx.x >> 6, lane = threadIdx.x & 63;
  int node = blockIdx.x * 4 + wave;
  if (node >= N) return;
  ushort4 u = *(const ushort4*)(P + (size_t)node * HIDD + lane * 4);
  float4 v = make_float4(b2f(u.x), b2f(u.y), b2f(u.z), b2f(u.w));
  float4 s = *(const float4*)(atS + lane * 4);
  float4 d = *(const float4*)(atD + lane * 4);
  float s1 = v.x * s.x + v.y * s.y + v.z * s.z + v.w * s.w;
  float s2 = v.x * d.x + v.y * d.y + v.z * d.z + v.w * d.w;
#pragma unroll
  for (int off = 32; off; off >>= 1) {
    s1 += __shfl_down(s1, off);
    s2 += __shfl_down(s2, off);
  }
  if (lane == 0) { asrc[node] = s1; adst[node] = s2; }
}

// ---- multi-block exclusive scan over deg ----
__global__ __launch_bounds__(256) void scan_p1(const int* __restrict__ deg,
                                               int* __restrict__ bsum, int N)
{
  int b = blockIdx.x, t = threadIdx.x;
  int i0 = b * 1024 + t * 4;
  int s = 0;
#pragma unroll
  for (int j = 0; j < 4; ++j) { int i = i0 + j; if (i < N) s += deg[i]; }
  __shared__ int red[256];
  red[t] = s;
  __syncthreads();
  for (int o = 128; o; o >>= 1) {
    if (t < o) red[t] += red[t + o];
    __syncthreads();
  }
  if (t == 0) bsum[b] = red[0];
}

__global__ __launch_bounds__(256) void scan_p2(int* __restrict__ bsum, int nb)
{
  __shared__ int sh[256];
  int t = threadIdx.x;
  int v = (t < nb) ? bsum[t] : 0;
  sh[t] = v;
  __syncthreads();
  for (int o = 1; o < 256; o <<= 1) {
    int u = (t >= o) ? sh[t - o] : 0;
    __syncthreads();
    sh[t] += u;
    __syncthreads();
  }
  if (t < nb) bsum[t] = sh[t] - v;   // exclusive
}

__global__ __launch_bounds__(256) void scan_p3(const int* __restrict__ deg,
                                               const int* __restrict__ bsum,
                                               int* __restrict__ offs, int* __restrict__ cur,
                                               int N, int nb)
{
  int b = blockIdx.x, t = threadIdx.x;
  int i0 = b * 1024 + t * 4;
  int v[4]; int s = 0;
#pragma unroll
  for (int j = 0; j < 4; ++j) { int i = i0 + j; v[j] = (i < N) ? deg[i] : 0; s += v[j]; }
  __shared__ int sh[256];
  sh[t] = s;
  __syncthreads();
  for (int o = 1; o < 256; o <<= 1) {
    int u = (t >= o) ? sh[t - o] : 0;
    __syncthreads();
    sh[t] += u;
    __syncthreads();
  }
  int run = bsum[b] + sh[t] - s;
#pragma unroll
  for (int j = 0; j < 4; ++j) {
    int i = i0 + j;
    if (i < N) { offs[i] = run; cur[i] = run; }
    run += v[j];
  }
  if (b == nb - 1 && t == 255) offs[N] = run;   // total = E
}

// ---- agg layer 1: wave/node, w computed at stage time, denominator in-loop ----
__global__ __launch_bounds__(256) void agg_elu2(
    const unsigned short* __restrict__ xp,
    const float* __restrict__ asrc, const float* __restrict__ adst,
    const int* __restrict__ srcP, const int* __restrict__ offs,
    unsigned short* __restrict__ hout, int N)
{
  __shared__ int   sS[4][64];
  __shared__ float sW[4][64];
  int wid = threadIdx.x >> 6, lane = threadIdx.x & 63;
  int node = blockIdx.x * 4 + wid;
  if (node >= N) return;
  const float ad = adst[node];
  int s0 = offs[node], s1 = offs[node + 1];
  float a0 = 0.f, a1 = 0.f, a2 = 0.f, a3 = 0.f, den = 0.f;
  for (int base = s0; base < s1; base += 64) {
    int cnt = s1 - base; if (cnt > 64) cnt = 64;
    if (lane < cnt) {
      int sv = srcP[base + lane];
      sS[wid][lane] = sv;
      sW[wid][lane] = edgew(asrc[sv] + ad);
    }
    asm volatile("s_waitcnt lgkmcnt(0)" ::: "memory");   // wave-local LDS RAW fence
    int j = 0;
    for (; j + 8 <= cnt; j += 8) {
      ushort4 u[8];
#pragma unroll
      for (int q = 0; q < 8; ++q)
        u[q] = *(const ushort4*)(xp + (size_t)sS[wid][j + q] * HIDD + lane * 4);
#pragma unroll
      for (int q = 0; q < 8; ++q) {
        float wv = sW[wid][j + q];
        den += wv;
        a0 += wv * b2f(u[q].x); a1 += wv * b2f(u[q].y);
        a2 += wv * b2f(u[q].z); a3 += wv * b2f(u[q].w);
      }
    }
    for (; j < cnt; ++j) {
      int   sv = sS[wid][j];
      float wv = sW[wid][j];
      den += wv;
      ushort4 u = *(const ushort4*)(xp + (size_t)sv * HIDD + lane * 4);
      a0 += wv * b2f(u.x); a1 += wv * b2f(u.y); a2 += wv * b2f(u.z); a3 += wv * b2f(u.w);
    }
  }
  float inv = 1.f / (den + 1e-16f);
  float r0 = a0 * inv, r1 = a1 * inv, r2 = a2 * inv, r3 = a3 * inv;
  r0 = r0 > 0.f ? r0 : expm1f(r0);
  r1 = r1 > 0.f ? r1 : expm1f(r1);
  r2 = r2 > 0.f ? r2 : expm1f(r2);
  r3 = r3 > 0.f ? r3 : expm1f(r3);
  ushort4 o; o.x = f2b(r0); o.y = f2b(r1); o.z = f2b(r2); o.w = f2b(r3);
  *(ushort4*)(hout + (size_t)node * HIDD + lane * 4) = o;
}

// ---- h2 = h1 @ W2 ([N,256]x[256,32]) -> adaptive out + bf16 copy ----
__global__ __launch_bounds__(256) void gemm_h2(
    const unsigned short* __restrict__ H1, const float* __restrict__ W2f,
    void* __restrict__ Out, unsigned short* __restrict__ h2b,
    const int* __restrict__ flags, int M)
{
  const int fb = flags[0];
  __shared__ float Bs[HIDD][33];
  __shared__ float As[8][HIDD];
  int tid = threadIdx.x;
  int tx = tid & 31, ty = tid >> 5;
  int row0 = blockIdx.x * 8;
#pragma unroll
  for (int j = 0; j < 32; ++j) {
    int idx = tid + 256 * j;
    Bs[idx >> 5][idx & 31] = W2f[idx];
  }
#pragma unroll
  for (int j = 0; j < 8; ++j) {
    int idx = tid + 256 * j;
    int r = idx >> 8, k = idx & 255;
    As[r][k] = (row0 + r < M) ? b2f(H1[(size_t)(row0 + r) * HIDD + k]) : 0.f;
  }
  __syncthreads();
  float acc = 0.f;
#pragma unroll 8
  for (int k = 0; k < HIDD; ++k) acc += As[ty][k] * Bs[k][tx];
  int row = row0 + ty;
  if (row < M) {
    size_t idx = (size_t)row * OUTD + tx;
    if (fb) ((unsigned short*)Out)[idx] = f2b(acc);
    else    ((float*)Out)[idx] = acc;
    h2b[idx] = f2b(acc);
  }
}

// ---- agg layer 2 on h2 [N,32] bf16 -> g2pad [N][64], w recomputed inline ----
__global__ __launch_bounds__(256) void agg_small(
    const unsigned short* __restrict__ h2b,
    const float* __restrict__ asrc, const float* __restrict__ adst,
    const int* __restrict__ srcP, const int* __restrict__ offs,
    unsigned short* __restrict__ g2pad, int N)
{
  int wid = threadIdx.x >> 6, lane = threadIdx.x & 63;
  int node = blockIdx.x * 4 + wid;
  if (node >= N) return;
  int grp = lane >> 4, cl = lane & 15;
  const float ad = adst[node];
  int s0 = offs[node], s1 = offs[node + 1];
  float a0 = 0.f, a1 = 0.f, den = 0.f;
  for (int e = s0 + grp; e < s1; e += 4) {
    int   sv = srcP[e];          // uniform across the 16-lane group (broadcast)
    float wv = edgew(asrc[sv] + ad);
    den += wv;
    ushort2 u = *(const ushort2*)(h2b + (size_t)sv * OUTD + cl * 2);
    a0 += wv * b2f(u.x);
    a1 += wv * b2f(u.y);
  }
  a0 += __shfl_xor(a0, 16); a0 += __shfl_xor(a0, 32);
  a1 += __shfl_xor(a1, 16); a1 += __shfl_xor(a1, 32);
  den += __shfl_xor(den, 16); den += __shfl_xor(den, 32);
  if (grp == 0) {
    float inv = 1.f / (den + 1e-16f);
    ushort2 o; o.x = f2b(a0 * inv); o.y = f2b(a1 * inv);
    *(ushort2*)(g2pad + (size_t)node * 64 + cl * 2) = o;
  } else if (grp == 1) {
    *(ushort2*)(g2pad + (size_t)node * 64 + 32 + cl * 2) = make_ushort2(0, 0);  // K-pad
  }
}

extern "C" void kernel_launch(void* const* d_in, const int* in_sizes, int n_in,
                              void* d_out, int out_size, void* d_ws, size_t ws_size,
                              hipStream_t stream)
{
  const void*         feat = d_in[0];
  const unsigned int* eidx = (const unsigned int*)d_in[1];
  const void*         W1   = d_in[2];
  const void*         W2   = d_in[3];
  const void*         aS   = d_in[4];
  const void*         aD   = d_in[5];

  const int N = in_sizes[0] / INDIM;
  const int E = in_sizes[1] / 2;
  const int M_pad = ((N + 127) / 128) * 128;
  const int nb = (N + 1023) / 1024;
  int shift = 11;
  while ((((N - 1) >> shift) + 1) > 64) ++shift;
  const int nslab = ((N - 1) >> shift) + 1;

  char* w = (char*)d_ws;
  auto alloc = [&](size_t bytes) -> char* {
    char* p = w; w += (bytes + 255) & ~(size_t)255; return p;
  };
  unsigned short* H     = (unsigned short*)alloc((size_t)M_pad * HIDD * 2);  // h1 / h3
  unsigned short* P     = (unsigned short*)alloc((size_t)M_pad * HIDD * 2);  // xp1
  unsigned short* h2b   = (unsigned short*)alloc((size_t)N * OUTD * 2);      // h2 bf16
  unsigned short* g2pad = (unsigned short*)alloc((size_t)M_pad * 64 * 2);    // agg(h2), K-padded
  float* asrc = (float*)alloc((size_t)N * 4);
  float* adst = (float*)alloc((size_t)N * 4);
  int*   srcP = (int*)alloc((size_t)E * 4);     // CSR-ordered edge src
  uint2* part = (uint2*)alloc((size_t)E * 8);   // slab-partitioned (src,dst)
  int*   deg  = (int*)alloc((size_t)N * 4);
  int*   offs = (int*)alloc((size_t)(N + 1) * 4);
  int*   cur  = (int*)alloc((size_t)N * 4);
  int*   bsum = (int*)alloc((size_t)(nb + 1) * 4);
  int*   slabCount = (int*)alloc(64 * 4);
  int*   slabOff   = (int*)alloc(65 * 4);
  int*   slabCur   = (int*)alloc(64 * 4);
  unsigned short* W1b   = (unsigned short*)alloc((size_t)INDIM * HIDD * 2); // [512][256]
  unsigned short* W1tb  = (unsigned short*)alloc((size_t)INDIM * HIDD * 2); // [256][512]
  unsigned short* W2b64 = (unsigned short*)alloc((size_t)HIDD * 64 * 2);    // [256][64]
  float* W2f  = (float*)alloc((size_t)HIDD * OUTD * 4);
  float* atS  = (float*)alloc((size_t)HIDD * 4);
  float* atD  = (float*)alloc((size_t)HIDD * 4);
  int*   flags = (int*)alloc(64);

  hipMemsetAsync(deg, 0, (size_t)N * 4, stream);
  hipMemsetAsync(slabCount, 0, 64 * 4, stream);

  probe_kernel<<<1, 256, 0, stream>>>((const unsigned int*)feat, eidx, flags);

  const int eb = (E + 255) / 256;
  // CSR build: deg+slab hist -> slab scan -> partition -> node scan -> pinned fill
  p1_kernel<<<eb, 256, 0, stream>>>(eidx, deg, slabCount, E, shift, nslab, flags);
  slabscan_kernel<<<1, 64, 0, stream>>>(slabCount, slabOff, slabCur, nslab);
  part_kernel<<<(E + PCH - 1) / PCH, 256, 0, stream>>>(eidx, slabCur, part, E, shift, nslab, flags);
  prep_weights<<<512, 256, 0, stream>>>(W1, W2, aS, aD, W1b, W1tb, W2f, W2b64, atS, atD, flags);
  scan_p1<<<nb, 256, 0, stream>>>(deg, bsum, N);
  scan_p2<<<1, 256, 0, stream>>>(bsum, nb);
  scan_p3<<<nb, 256, 0, stream>>>(deg, bsum, offs, cur, N, nb);
  fill2_kernel<<<512, 256, 0, stream>>>(part, slabOff, cur, srcP, nslab);

  const int mb = (N + 127) / 128;

  // xp1 = feat @ W1 (f32 A converted in staging, or bf16 gld16 per flag)
  gemm_nt2<1, 0, 0><<<dim3(HIDD / 128, mb), 256, 0, stream>>>(
      feat, W1tb, P, nullptr, 0, flags, N, HIDD, INDIM);

  rowdots<<<(N + 3) / 4, 256, 0, stream>>>(P, atS, atD, asrc, adst, N);

  // GAT layer 1: h1 = elu(agg(xp1)/denom)
  agg_elu2<<<(N + 3) / 4, 256, 0, stream>>>(P, asrc, adst, srcP, offs, H, N);

  // h2 = h1 @ W2 -> output 0 (+ bf16 copy for layer-2 agg)
  gemm_h2<<<(N + 7) / 8, 256, 0, stream>>>(H, W2f, d_out, h2b, flags, N);

  // GAT layer 2, commuted: g2 = agg(h2) [N,32->64pad]
  agg_small<<<(N + 3) / 4, 256, 0, stream>>>(h2b, asrc, adst, srcP, offs, g2pad, N);

  // h3 = elu(g2 @ W2^T) via MFMA GEMM
  gemm_nt2<0, 0, 1><<<dim3(HIDD / 128, mb), 256, 0, stream>>>(
      g2pad, W2b64, H, nullptr, 0, flags, N, HIDD, 64);

  // h4 = h3 @ W1^T -> output 1 (adaptive)
  gemm_nt2<0, 1, 0><<<dim3(INDIM / 128, mb), 256, 0, stream>>>(
      H, W1b, nullptr, d_out, (size_t)N * OUTD, flags, N, INDIM, HIDD);
}

// Round 10
// 720.401 us; speedup vs baseline: 1.1356x; 1.1356x over previous
//
#include <hip/hip_runtime.h>
#include <cstdint>
#include <cstddef>

#define INDIM 512
#define HIDD  256
#define OUTD  32
#define PCH   4096      // edges per radix block
#define SLABN 2048      // nodes per slab (shift 11); nslab <= 64

typedef __attribute__((ext_vector_type(4))) float f32x4;
typedef __attribute__((ext_vector_type(8))) short bf16x8;

// ---- bf16 <-> f32 helpers ----
static inline __device__ float b2f(unsigned short u) {
  union { float f; unsigned int i; } v; v.i = ((unsigned int)u) << 16; return v.f;
}
static inline __device__ unsigned short f2b(float f) {
  union { float f; unsigned int i; } v; v.f = f;
  unsigned int x = v.i;
  x += 0x7fffu + ((x >> 16) & 1u);   // round-to-nearest-even
  return (unsigned short)(x >> 16);
}

// edge weight: exp(sigmoid(x)) — SAME formula in both agg kernels
static inline __device__ float edgew(float x) {
  float al = 1.f / (1.f + __expf(-x));
  return __expf(al);
}

// async global->LDS, 16B per lane. LDS dest = wave-uniform base + lane*16.
static __device__ __forceinline__ void gld16(const unsigned short* g, unsigned short* l) {
  __builtin_amdgcn_global_load_lds(
      (const __attribute__((address_space(1))) void*)g,
      (__attribute__((address_space(3))) void*)l, 16, 0, 0);
}

// ---- runtime dtype probe ----
__global__ __launch_bounds__(256) void probe_kernel(
    const unsigned int* __restrict__ feat, const unsigned int* __restrict__ eidx,
    int* __restrict__ flags)
{
  int t = threadIdx.x;
  __shared__ int cnt, oddnz;
  if (t == 0) { cnt = 0; oddnz = 0; }
  __syncthreads();
  unsigned int w = feat[t];
  unsigned short lo = (unsigned short)(w & 0xFFFFu);
  int e = (lo >> 7) & 0xFF;
  int plausible = ((lo & 0x7FFF) == 0) || (e >= 0x60 && e <= 0x9F);
  atomicAdd(&cnt, plausible);
  if (t & 1) { if (eidx[t] != 0u) atomicAdd(&oddnz, 1); }
  __syncthreads();
  if (t == 0) { flags[0] = (cnt >= 192) ? 1 : 0; flags[1] = (oddnz == 0) ? 1 : 0; }
}

// ---- radix pass A: per-block slab counts (LDS hist, plain global writes) ----
__global__ __launch_bounds__(256) void cnt_kernel(
    const unsigned int* __restrict__ eidx, int* __restrict__ bcnt,
    int E, const int* __restrict__ flags)
{
  __shared__ int hist[64];
  int t = threadIdx.x;
  if (t < 64) hist[t] = 0;
  __syncthreads();
  int e0 = blockIdx.x * PCH;
  const int i64 = flags[1];
  for (int i = t; i < PCH; i += 256) {
    int e = e0 + i; if (e >= E) break;
    int d = i64 ? (int)eidx[2 * ((size_t)E + e)] : (int)eidx[(size_t)E + e];
    atomicAdd(&hist[d >> 11], 1);
  }
  __syncthreads();
  if (t < 64) bcnt[blockIdx.x * 64 + t] = hist[t];
}

// ---- radix pass B: bcnt -> within-slab block prefixes; slabOff exclusive scan ----
__global__ __launch_bounds__(64) void bscan_kernel(
    int* __restrict__ bcnt, int* __restrict__ slabOff, int npb)
{
  int t = threadIdx.x;           // lane = slab
  int run = 0;
  for (int b = 0; b < npb; ++b) {
    int v = bcnt[b * 64 + t];
    bcnt[b * 64 + t] = run;      // within-slab prefix
    run += v;
  }
  int inc = run;
#pragma unroll
  for (int o = 1; o < 64; o <<= 1) {
    int u = __shfl_up(inc, o);
    if (t >= o) inc += u;
  }
  slabOff[t] = inc - run;        // exclusive
  if (t == 63) slabOff[64] = inc;   // = E
}

// ---- radix pass C: scatter (src,dst) into slab-contiguous part[] ----
__global__ __launch_bounds__(256) void scat_kernel(
    const unsigned int* __restrict__ eidx, const int* __restrict__ bcnt,
    const int* __restrict__ slabOff, uint2* __restrict__ part,
    int E, const int* __restrict__ flags)
{
  __shared__ int cur[64];
  int t = threadIdx.x;
  if (t < 64) cur[t] = slabOff[t] + bcnt[blockIdx.x * 64 + t];
  __syncthreads();
  int e0 = blockIdx.x * PCH;
  const int i64 = flags[1];
  for (int i = t; i < PCH; i += 256) {
    int e = e0 + i; if (e >= E) break;
    int s, d;
    if (i64) { s = (int)eidx[2 * (size_t)e]; d = (int)eidx[2 * ((size_t)E + e)]; }
    else     { s = (int)eidx[e];             d = (int)eidx[(size_t)E + e]; }
    int pos = atomicAdd(&cur[d >> 11], 1);
    part[pos] = make_uint2((unsigned)s, (unsigned)d);
  }
}

// ---- radix pass D: per-slab CSR build fully in LDS (deg, scan, fill) ----
__global__ __launch_bounds__(256) void slabcsr_kernel(
    const uint2* __restrict__ part, const int* __restrict__ slabOff,
    int* __restrict__ offs, int* __restrict__ srcP, int N, int nslab)
{
  __shared__ int deg[SLABN];
  __shared__ int wsum[4];
  int sl = blockIdx.x, t = threadIdx.x;
  int n0 = sl << 11;
  int nn = N - n0; if (nn > SLABN) nn = SLABN;
  int s0 = slabOff[sl], s1 = slabOff[sl + 1];
  for (int i = t; i < SLABN; i += 256) deg[i] = 0;
  __syncthreads();
  for (int i = s0 + t; i < s1; i += 256)
    atomicAdd(&deg[(int)part[i].y - n0], 1);
  __syncthreads();
  // block-wide exclusive scan of deg[0..SLABN): 8 elems/thread
  int loc[8]; int bi = t * 8; int s = 0;
#pragma unroll
  for (int j = 0; j < 8; ++j) { loc[j] = deg[bi + j]; s += loc[j]; }
  int ws = s;
#pragma unroll
  for (int o = 1; o < 64; o <<= 1) {
    int u = __shfl_up(ws, o);
    if ((t & 63) >= o) ws += u;
  }
  if ((t & 63) == 63) wsum[t >> 6] = ws;
  __syncthreads();
  if (t < 4) {
    int v = wsum[t], inc = v;
#pragma unroll
    for (int o = 1; o < 4; o <<= 1) {
      int u = __shfl_up(inc, o);
      if (t >= o) inc += u;
    }
    wsum[t] = inc - v;
  }
  __syncthreads();
  int run = wsum[t >> 6] + (ws - s);   // thread-exclusive base
#pragma unroll
  for (int j = 0; j < 8; ++j) {
    int idx = bi + j;
    int v = loc[j];
    deg[idx] = run;                    // local cursor init
    if (idx < nn) offs[n0 + idx] = s0 + run;
    run += v;
  }
  __syncthreads();
  for (int i = s0 + t; i < s1; i += 256) {
    uint2 p = part[i];
    int pos = s0 + atomicAdd(&deg[(int)p.y - n0], 1);
    srcP[pos] = (int)p.x;
  }
  if (sl == nslab - 1 && t == 0) offs[N] = s1;
}

static inline __device__ float ldadapt(const void* p, size_t i, int isbf) {
  return isbf ? b2f(((const unsigned short*)p)[i]) : ((const float*)p)[i];
}

// ---- weight prep: W1b, W1tb, W2f, W2b64 ([256][64] bf16, zero-padded K), att ----
__global__ __launch_bounds__(256) void prep_weights(
    const void* __restrict__ W1, const void* __restrict__ W2,
    const void* __restrict__ aS, const void* __restrict__ aD,
    unsigned short* __restrict__ W1b, unsigned short* __restrict__ W1tb,
    float* __restrict__ W2f, unsigned short* __restrict__ W2b64,
    float* __restrict__ atS, float* __restrict__ atD,
    const int* __restrict__ flags)
{
  const int fb = flags[0];
  int i = blockIdx.x * 256 + threadIdx.x;
  if (i < INDIM * HIDD) {               // W1: [512][256]
    int r = i >> 8, c = i & 255;
    float w0 = ldadapt(W1, i, fb);
    unsigned short wb = f2b(w0);
    W1b[i] = wb;                        // Bt for h4: [512 rows][256 k]
    W1tb[c * INDIM + r] = wb;           // Bt for xp1: [256 rows][512 k]
  }
  if (i < HIDD * OUTD) {                // W2: [256][32]
    int r = i >> 5, c = i & 31;
    float w0 = ldadapt(W2, i, fb);
    W2f[i] = w0;
    W2b64[r * 64 + c] = f2b(w0);        // Bt for h3: [256 rows][64 k], upper 32 zero
    W2b64[r * 64 + 32 + c] = 0;
  }
  if (i < HIDD) { atS[i] = ldadapt(aS, i, fb); atD[i] = ldadapt(aD, i, fb); }
}

// =====================================================================
// m97-structure MFMA NT GEMM: C[M][Nn] = A[M][K] @ Bt[Nn][K]^T.
// AMODE:   0 = A bf16 ws buffer (gld16, rows to M_pad readable)
//          1 = A external input: fb ? bf16 gld16 : f32 reg-stage+convert (row-clamped)
// OUTMODE: 0 = bf16 to Cb; 1 = adaptive (flags[0]) to Out+outOff
// EPI:     0 = none; 1 = ELU before store
// =====================================================================
template<int AMODE, int OUTMODE, int EPI>
__global__ __launch_bounds__(256) void gemm_nt2(
    const void* __restrict__ Av, const unsigned short* __restrict__ Bt,
    unsigned short* __restrict__ Cb, void* __restrict__ Out, size_t outOff,
    const int* __restrict__ flags, int M, int Nn, int K)
{
  __shared__ unsigned short Als[128 * 64];
  __shared__ unsigned short Bls[128 * 64];
  const int tid = threadIdx.x, lane = tid & 63, wid = tid >> 6;
  const int wr = wid >> 1, wc = wid & 1;
  const int rowBase = blockIdx.y * 128, colBase = blockIdx.x * 128;
  const int fb = flags[0];

  const int srow = (lane >> 3), sg = lane & 7;

  f32x4 acc[4][4] = {};

  for (int kt = 0; kt < K; kt += 64) {
    if (AMODE == 1 && !fb) {
      const float* Af = (const float*)Av;
#pragma unroll
      for (int i = 0; i < 4; ++i) {
        int row = wid * 32 + i * 8 + srow;
        int gr = rowBase + row; if (gr > M - 1) gr = M - 1;
        const float* sp = Af + (size_t)gr * K + kt + sg * 8;
        float4 lo = *(const float4*)sp;
        float4 hi = *(const float4*)(sp + 4);
        union { unsigned short us[8]; int4 v; } cv;
        cv.us[0] = f2b(lo.x); cv.us[1] = f2b(lo.y); cv.us[2] = f2b(lo.z); cv.us[3] = f2b(lo.w);
        cv.us[4] = f2b(hi.x); cv.us[5] = f2b(hi.y); cv.us[6] = f2b(hi.z); cv.us[7] = f2b(hi.w);
        *(int4*)(Als + (wid * 4 + i) * 512 + lane * 8) = cv.v;
      }
    } else {
      const unsigned short* Ab = (const unsigned short*)Av;
#pragma unroll
      for (int i = 0; i < 4; ++i) {
        int row = wid * 32 + i * 8 + srow;
        int gr = rowBase + row;
        if (AMODE == 1 && gr > M - 1) gr = M - 1;   // external input: clamp
        gld16(Ab + (size_t)gr * K + kt + sg * 8, Als + (wid * 4 + i) * 512);
      }
    }
#pragma unroll
    for (int i = 0; i < 4; ++i) {
      int row = wid * 32 + i * 8 + srow;
      gld16(Bt + (size_t)(colBase + row) * K + kt + sg * 8, Bls + (wid * 4 + i) * 512);
    }
    __syncthreads();

    bf16x8 af[4], bfr[4];
#pragma unroll
    for (int ks = 0; ks < 2; ++ks) {
      int g = ks * 4 + (lane >> 4);
#pragma unroll
      for (int mi = 0; mi < 4; ++mi) {
        int row = wr * 64 + mi * 16 + (lane & 15);
        af[mi] = *(const bf16x8*)(Als + row * 64 + g * 8);
      }
#pragma unroll
      for (int ni = 0; ni < 4; ++ni) {
        int row = wc * 64 + ni * 16 + (lane & 15);
        bfr[ni] = *(const bf16x8*)(Bls + row * 64 + g * 8);
      }
#pragma unroll
      for (int mi = 0; mi < 4; ++mi)
#pragma unroll
        for (int ni = 0; ni < 4; ++ni)
          acc[mi][ni] = __builtin_amdgcn_mfma_f32_16x16x32_bf16(af[mi], bfr[ni], acc[mi][ni], 0, 0, 0);
    }
    __syncthreads();
  }

  // C/D: col = lane&15, row = (lane>>4)*4 + reg
#pragma unroll
  for (int mi = 0; mi < 4; ++mi) {
    int r0 = rowBase + wr * 64 + mi * 16 + (lane >> 4) * 4;
#pragma unroll
    for (int ni = 0; ni < 4; ++ni) {
      int c = colBase + wc * 64 + ni * 16 + (lane & 15);
#pragma unroll
      for (int v = 0; v < 4; ++v) {
        int r = r0 + v;
        if (r < M) {
          size_t idx = (size_t)r * Nn + c;
          float x = acc[mi][ni][v];
          if (EPI) x = x > 0.f ? x : expm1f(x);
          if (OUTMODE == 0) Cb[idx] = f2b(x);
          else {
            if (fb) ((unsigned short*)Out)[outOff + idx] = f2b(x);
            else    ((float*)Out)[outOff + idx] = x;
          }
        }
      }
    }
  }
}

// ---- a_src / a_dst: one wave per node, dot(xp1_row, att); P is bf16 ----
__global__ __launch_bounds__(256) void rowdots(
    const unsigned short* __restrict__ P, const float* __restrict__ atS,
    const float* __restrict__ atD,
    float* __restrict__ asrc, float* __restrict__ adst, int N)
{
  int wave = threadIdx.x >> 6, lane = threadIdx.x & 63;
  int node = blockIdx.x * 4 + wave;
  if (node >= N) return;
  ushort4 u = *(const ushort4*)(P + (size_t)node * HIDD + lane * 4);
  float4 v = make_float4(b2f(u.x), b2f(u.y), b2f(u.z), b2f(u.w));
  float4 s = *(const float4*)(atS + lane * 4);
  float4 d = *(const float4*)(atD + lane * 4);
  float s1 = v.x * s.x + v.y * s.y + v.z * s.z + v.w * s.w;
  float s2 = v.x * d.x + v.y * d.y + v.z * d.z + v.w * d.w;
#pragma unroll
  for (int off = 32; off; off >>= 1) {
    s1 += __shfl_down(s1, off);
    s2 += __shfl_down(s2, off);
  }
  if (lane == 0) { asrc[node] = s1; adst[node] = s2; }
}

// ---- agg layer 1: wave/node, w computed at stage time, denominator in-loop ----
__global__ __launch_bounds__(256) void agg_elu2(
    const unsigned short* __restrict__ xp,
    const float* __restrict__ asrc, const float* __restrict__ adst,
    const int* __restrict__ srcP, const int* __restrict__ offs,
    unsigned short* __restrict__ hout, int N)
{
  __shared__ int   sS[4][64];
  __shared__ float sW[4][64];
  int wid = threadIdx.x >> 6, lane = threadIdx.x & 63;
  int node = blockIdx.x * 4 + wid;
  if (node >= N) return;
  const float ad = adst[node];
  int s0 = offs[node], s1 = offs[node + 1];
  float a0 = 0.f, a1 = 0.f, a2 = 0.f, a3 = 0.f, den = 0.f;
  for (int base = s0; base < s1; base += 64) {
    int cnt = s1 - base; if (cnt > 64) cnt = 64;
    if (lane < cnt) {
      int sv = srcP[base + lane];
      sS[wid][lane] = sv;
      sW[wid][lane] = edgew(asrc[sv] + ad);
    }
    asm volatile("s_waitcnt lgkmcnt(0)" ::: "memory");   // wave-local LDS RAW fence
    int j = 0;
    for (; j + 8 <= cnt; j += 8) {
      ushort4 u[8];
#pragma unroll
      for (int q = 0; q < 8; ++q)
        u[q] = *(const ushort4*)(xp + (size_t)sS[wid][j + q] * HIDD + lane * 4);
#pragma unroll
      for (int q = 0; q < 8; ++q) {
        float wv = sW[wid][j + q];
        den += wv;
        a0 += wv * b2f(u[q].x); a1 += wv * b2f(u[q].y);
        a2 += wv * b2f(u[q].z); a3 += wv * b2f(u[q].w);
      }
    }
    for (; j < cnt; ++j) {
      int   sv = sS[wid][j];
      float wv = sW[wid][j];
      den += wv;
      ushort4 u = *(const ushort4*)(xp + (size_t)sv * HIDD + lane * 4);
      a0 += wv * b2f(u.x); a1 += wv * b2f(u.y); a2 += wv * b2f(u.z); a3 += wv * b2f(u.w);
    }
  }
  float inv = 1.f / (den + 1e-16f);
  float r0 = a0 * inv, r1 = a1 * inv, r2 = a2 * inv, r3 = a3 * inv;
  r0 = r0 > 0.f ? r0 : expm1f(r0);
  r1 = r1 > 0.f ? r1 : expm1f(r1);
  r2 = r2 > 0.f ? r2 : expm1f(r2);
  r3 = r3 > 0.f ? r3 : expm1f(r3);
  ushort4 o; o.x = f2b(r0); o.y = f2b(r1); o.z = f2b(r2); o.w = f2b(r3);
  *(ushort4*)(hout + (size_t)node * HIDD + lane * 4) = o;
}

// ---- h2 = h1 @ W2 ([N,256]x[256,32]) -> adaptive out + bf16 copy ----
__global__ __launch_bounds__(256) void gemm_h2(
    const unsigned short* __restrict__ H1, const float* __restrict__ W2f,
    void* __restrict__ Out, unsigned short* __restrict__ h2b,
    const int* __restrict__ flags, int M)
{
  const int fb = flags[0];
  __shared__ float Bs[HIDD][33];
  __shared__ float As[8][HIDD];
  int tid = threadIdx.x;
  int tx = tid & 31, ty = tid >> 5;
  int row0 = blockIdx.x * 8;
#pragma unroll
  for (int j = 0; j < 32; ++j) {
    int idx = tid + 256 * j;
    Bs[idx >> 5][idx & 31] = W2f[idx];
  }
#pragma unroll
  for (int j = 0; j < 8; ++j) {
    int idx = tid + 256 * j;
    int r = idx >> 8, k = idx & 255;
    As[r][k] = (row0 + r < M) ? b2f(H1[(size_t)(row0 + r) * HIDD + k]) : 0.f;
  }
  __syncthreads();
  float acc = 0.f;
#pragma unroll 8
  for (int k = 0; k < HIDD; ++k) acc += As[ty][k] * Bs[k][tx];
  int row = row0 + ty;
  if (row < M) {
    size_t idx = (size_t)row * OUTD + tx;
    if (fb) ((unsigned short*)Out)[idx] = f2b(acc);
    else    ((float*)Out)[idx] = acc;
    h2b[idx] = f2b(acc);
  }
}

// ---- agg layer 2 on h2 [N,32] bf16 -> g2pad [N][64], w recomputed inline ----
__global__ __launch_bounds__(256) void agg_small(
    const unsigned short* __restrict__ h2b,
    const float* __restrict__ asrc, const float* __restrict__ adst,
    const int* __restrict__ srcP, const int* __restrict__ offs,
    unsigned short* __restrict__ g2pad, int N)
{
  int wid = threadIdx.x >> 6, lane = threadIdx.x & 63;
  int node = blockIdx.x * 4 + wid;
  if (node >= N) return;
  int grp = lane >> 4, cl = lane & 15;
  const float ad = adst[node];
  int s0 = offs[node], s1 = offs[node + 1];
  float a0 = 0.f, a1 = 0.f, den = 0.f;
  for (int e = s0 + grp; e < s1; e += 4) {
    int   sv = srcP[e];          // uniform across the 16-lane group (broadcast)
    float wv = edgew(asrc[sv] + ad);
    den += wv;
    ushort2 u = *(const ushort2*)(h2b + (size_t)sv * OUTD + cl * 2);
    a0 += wv * b2f(u.x);
    a1 += wv * b2f(u.y);
  }
  a0 += __shfl_xor(a0, 16); a0 += __shfl_xor(a0, 32);
  a1 += __shfl_xor(a1, 16); a1 += __shfl_xor(a1, 32);
  den += __shfl_xor(den, 16); den += __shfl_xor(den, 32);
  if (grp == 0) {
    float inv = 1.f / (den + 1e-16f);
    ushort2 o; o.x = f2b(a0 * inv); o.y = f2b(a1 * inv);
    *(ushort2*)(g2pad + (size_t)node * 64 + cl * 2) = o;
  } else if (grp == 1) {
    *(ushort2*)(g2pad + (size_t)node * 64 + 32 + cl * 2) = make_ushort2(0, 0);  // K-pad
  }
}

extern "C" void kernel_launch(void* const* d_in, const int* in_sizes, int n_in,
                              void* d_out, int out_size, void* d_ws, size_t ws_size,
                              hipStream_t stream)
{
  const void*         feat = d_in[0];
  const unsigned int* eidx = (const unsigned int*)d_in[1];
  const void*         W1   = d_in[2];
  const void*         W2   = d_in[3];
  const void*         aS   = d_in[4];
  const void*         aD   = d_in[5];

  const int N = in_sizes[0] / INDIM;
  const int E = in_sizes[1] / 2;
  const int M_pad = ((N + 127) / 128) * 128;
  const int nslab = (N + SLABN - 1) / SLABN;   // 49 for N=100000; must be <= 64
  const int npb = (E + PCH - 1) / PCH;

  char* w = (char*)d_ws;
  auto alloc = [&](size_t bytes) -> char* {
    char* p = w; w += (bytes + 255) & ~(size_t)255; return p;
  };
  unsigned short* H     = (unsigned short*)alloc((size_t)M_pad * HIDD * 2);  // h1 / h3
  unsigned short* P     = (unsigned short*)alloc((size_t)M_pad * HIDD * 2);  // xp1
  unsigned short* h2b   = (unsigned short*)alloc((size_t)N * OUTD * 2);      // h2 bf16
  unsigned short* g2pad = (unsigned short*)alloc((size_t)M_pad * 64 * 2);    // agg(h2), K-padded
  float* asrc = (float*)alloc((size_t)N * 4);
  float* adst = (float*)alloc((size_t)N * 4);
  int*   srcP = (int*)alloc((size_t)E * 4);     // CSR-ordered edge src
  uint2* part = (uint2*)alloc((size_t)E * 8);   // slab-partitioned (src,dst)
  int*   offs = (int*)alloc((size_t)(N + 1) * 4);
  int*   bcnt = (int*)alloc((size_t)npb * 64 * 4);
  int*   slabOff = (int*)alloc(65 * 4);
  unsigned short* W1b   = (unsigned short*)alloc((size_t)INDIM * HIDD * 2); // [512][256]
  unsigned short* W1tb  = (unsigned short*)alloc((size_t)INDIM * HIDD * 2); // [256][512]
  unsigned short* W2b64 = (unsigned short*)alloc((size_t)HIDD * 64 * 2);    // [256][64]
  float* W2f  = (float*)alloc((size_t)HIDD * OUTD * 4);
  float* atS  = (float*)alloc((size_t)HIDD * 4);
  float* atD  = (float*)alloc((size_t)HIDD * 4);
  int*   flags = (int*)alloc(64);

  probe_kernel<<<1, 256, 0, stream>>>((const unsigned int*)feat, eidx, flags);

  // CSR build: radix by dst-slab, then slab-local CSR in LDS (no global atomics)
  cnt_kernel<<<npb, 256, 0, stream>>>(eidx, bcnt, E, flags);
  bscan_kernel<<<1, 64, 0, stream>>>(bcnt, slabOff, npb);
  scat_kernel<<<npb, 256, 0, stream>>>(eidx, bcnt, slabOff, part, E, flags);
  slabcsr_kernel<<<nslab, 256, 0, stream>>>(part, slabOff, offs, srcP, N, nslab);

  prep_weights<<<512, 256, 0, stream>>>(W1, W2, aS, aD, W1b, W1tb, W2f, W2b64, atS, atD, flags);

  const int mb = (N + 127) / 128;

  // xp1 = feat @ W1 (f32 A converted in staging, or bf16 gld16 per flag)
  gemm_nt2<1, 0, 0><<<dim3(HIDD / 128, mb), 256, 0, stream>>>(
      feat, W1tb, P, nullptr, 0, flags, N, HIDD, INDIM);

  rowdots<<<(N + 3) / 4, 256, 0, stream>>>(P, atS, atD, asrc, adst, N);

  // GAT layer 1: h1 = elu(agg(xp1)/denom)
  agg_elu2<<<(N + 3) / 4, 256, 0, stream>>>(P, asrc, adst, srcP, offs, H, N);

  // h2 = h1 @ W2 -> output 0 (+ bf16 copy for layer-2 agg)
  gemm_h2<<<(N + 7) / 8, 256, 0, stream>>>(H, W2f, d_out, h2b, flags, N);

  // GAT layer 2, commuted: g2 = agg(h2) [N,32->64pad]
  agg_small<<<(N + 3) / 4, 256, 0, stream>>>(h2b, asrc, adst, srcP, offs, g2pad, N);

  // h3 = elu(g2 @ W2^T) via MFMA GEMM
  gemm_nt2<0, 0, 1><<<dim3(HIDD / 128, mb), 256, 0, stream>>>(
      g2pad, W2b64, H, nullptr, 0, flags, N, HIDD, 64);

  // h4 = h3 @ W1^T -> output 1 (adaptive)
  gemm_nt2<0, 1, 0><<<dim3(INDIM / 128, mb), 256, 0, stream>>>(
      H, W1b, nullptr, d_out, (size_t)N * OUTD, flags, N, INDIM, HIDD);
}

// Round 11
// 704.660 us; speedup vs baseline: 1.1610x; 1.0223x over previous
//
#include <hip/hip_runtime.h>
#include <cstdint>
#include <cstddef>

#define INDIM 512
#define HIDD  256
#define OUTD  32
#define PCH   4096      // edges per radix block
#define SLABN 2048      // nodes per slab (shift 11); nslab <= 64

typedef __attribute__((ext_vector_type(4))) float f32x4;
typedef __attribute__((ext_vector_type(8))) short bf16x8;

// ---- bf16 <-> f32 helpers ----
static inline __device__ float b2f(unsigned short u) {
  union { float f; unsigned int i; } v; v.i = ((unsigned int)u) << 16; return v.f;
}
static inline __device__ unsigned short f2b(float f) {
  union { float f; unsigned int i; } v; v.f = f;
  unsigned int x = v.i;
  x += 0x7fffu + ((x >> 16) & 1u);   // round-to-nearest-even
  return (unsigned short)(x >> 16);
}

// edge weight: exp(sigmoid(x)) — SAME formula in both agg kernels
static inline __device__ float edgew(float x) {
  float al = 1.f / (1.f + __expf(-x));
  return __expf(al);
}

// async global->LDS, 16B per lane. LDS dest = wave-uniform base + lane*16.
static __device__ __forceinline__ void gld16(const unsigned short* g, unsigned short* l) {
  __builtin_amdgcn_global_load_lds(
      (const __attribute__((address_space(1))) void*)g,
      (__attribute__((address_space(3))) void*)l, 16, 0, 0);
}

// ---- runtime dtype probe ----
__global__ __launch_bounds__(256) void probe_kernel(
    const unsigned int* __restrict__ feat, const unsigned int* __restrict__ eidx,
    int* __restrict__ flags)
{
  int t = threadIdx.x;
  __shared__ int cnt, oddnz;
  if (t == 0) { cnt = 0; oddnz = 0; }
  __syncthreads();
  unsigned int w = feat[t];
  unsigned short lo = (unsigned short)(w & 0xFFFFu);
  int e = (lo >> 7) & 0xFF;
  int plausible = ((lo & 0x7FFF) == 0) || (e >= 0x60 && e <= 0x9F);
  atomicAdd(&cnt, plausible);
  if (t & 1) { if (eidx[t] != 0u) atomicAdd(&oddnz, 1); }
  __syncthreads();
  if (t == 0) { flags[0] = (cnt >= 192) ? 1 : 0; flags[1] = (oddnz == 0) ? 1 : 0; }
}

// ---- radix pass A: per-block slab counts (LDS hist, plain global writes) ----
__global__ __launch_bounds__(256) void cnt_kernel(
    const unsigned int* __restrict__ eidx, int* __restrict__ bcnt,
    int E, const int* __restrict__ flags)
{
  __shared__ int hist[64];
  int t = threadIdx.x;
  if (t < 64) hist[t] = 0;
  __syncthreads();
  int e0 = blockIdx.x * PCH;
  const int i64 = flags[1];
  for (int i = t; i < PCH; i += 256) {
    int e = e0 + i; if (e >= E) break;
    int d = i64 ? (int)eidx[2 * ((size_t)E + e)] : (int)eidx[(size_t)E + e];
    atomicAdd(&hist[d >> 11], 1);
  }
  __syncthreads();
  if (t < 64) bcnt[blockIdx.x * 64 + t] = hist[t];
}

// ---- radix pass B: bcnt -> within-slab block prefixes; slabOff exclusive scan ----
__global__ __launch_bounds__(64) void bscan_kernel(
    int* __restrict__ bcnt, int* __restrict__ slabOff, int npb)
{
  int t = threadIdx.x;           // lane = slab
  int run = 0;
  for (int b = 0; b < npb; ++b) {
    int v = bcnt[b * 64 + t];
    bcnt[b * 64 + t] = run;      // within-slab prefix
    run += v;
  }
  int inc = run;
#pragma unroll
  for (int o = 1; o < 64; o <<= 1) {
    int u = __shfl_up(inc, o);
    if (t >= o) inc += u;
  }
  slabOff[t] = inc - run;        // exclusive
  if (t == 63) slabOff[64] = inc;   // = E
}

// ---- radix pass C: scatter (src,dst) into slab-contiguous part[] ----
__global__ __launch_bounds__(256) void scat_kernel(
    const unsigned int* __restrict__ eidx, const int* __restrict__ bcnt,
    const int* __restrict__ slabOff, uint2* __restrict__ part,
    int E, const int* __restrict__ flags)
{
  __shared__ int cur[64];
  int t = threadIdx.x;
  if (t < 64) cur[t] = slabOff[t] + bcnt[blockIdx.x * 64 + t];
  __syncthreads();
  int e0 = blockIdx.x * PCH;
  const int i64 = flags[1];
  for (int i = t; i < PCH; i += 256) {
    int e = e0 + i; if (e >= E) break;
    int s, d;
    if (i64) { s = (int)eidx[2 * (size_t)e]; d = (int)eidx[2 * ((size_t)E + e)]; }
    else     { s = (int)eidx[e];             d = (int)eidx[(size_t)E + e]; }
    int pos = atomicAdd(&cur[d >> 11], 1);
    part[pos] = make_uint2((unsigned)s, (unsigned)d);
  }
}

// ---- radix pass D: per-slab CSR build fully in LDS (deg, scan, fill) ----
__global__ __launch_bounds__(256) void slabcsr_kernel(
    const uint2* __restrict__ part, const int* __restrict__ slabOff,
    int* __restrict__ offs, int* __restrict__ srcP, int N, int nslab)
{
  __shared__ int deg[SLABN];
  __shared__ int wsum[4];
  int sl = blockIdx.x, t = threadIdx.x;
  int n0 = sl << 11;
  int nn = N - n0; if (nn > SLABN) nn = SLABN;
  int s0 = slabOff[sl], s1 = slabOff[sl + 1];
  for (int i = t; i < SLABN; i += 256) deg[i] = 0;
  __syncthreads();
  for (int i = s0 + t; i < s1; i += 256)
    atomicAdd(&deg[(int)part[i].y - n0], 1);
  __syncthreads();
  // block-wide exclusive scan of deg[0..SLABN): 8 elems/thread
  int loc[8]; int bi = t * 8; int s = 0;
#pragma unroll
  for (int j = 0; j < 8; ++j) { loc[j] = deg[bi + j]; s += loc[j]; }
  int ws = s;
#pragma unroll
  for (int o = 1; o < 64; o <<= 1) {
    int u = __shfl_up(ws, o);
    if ((t & 63) >= o) ws += u;
  }
  if ((t & 63) == 63) wsum[t >> 6] = ws;
  __syncthreads();
  if (t < 4) {
    int v = wsum[t], inc = v;
#pragma unroll
    for (int o = 1; o < 4; o <<= 1) {
      int u = __shfl_up(inc, o);
      if (t >= o) inc += u;
    }
    wsum[t] = inc - v;
  }
  __syncthreads();
  int run = wsum[t >> 6] + (ws - s);   // thread-exclusive base
#pragma unroll
  for (int j = 0; j < 8; ++j) {
    int idx = bi + j;
    int v = loc[j];
    deg[idx] = run;                    // local cursor init
    if (idx < nn) offs[n0 + idx] = s0 + run;
    run += v;
  }
  __syncthreads();
  for (int i = s0 + t; i < s1; i += 256) {
    uint2 p = part[i];
    int pos = s0 + atomicAdd(&deg[(int)p.y - n0], 1);
    srcP[pos] = (int)p.x;
  }
  if (sl == nslab - 1 && t == 0) offs[N] = s1;
}

static inline __device__ float ldadapt(const void* p, size_t i, int isbf) {
  return isbf ? b2f(((const unsigned short*)p)[i]) : ((const float*)p)[i];
}

// ---- weight prep: W1b, W1tb, W2f, W2b64 ([256][64] bf16, zero-padded K), att ----
__global__ __launch_bounds__(256) void prep_weights(
    const void* __restrict__ W1, const void* __restrict__ W2,
    const void* __restrict__ aS, const void* __restrict__ aD,
    unsigned short* __restrict__ W1b, unsigned short* __restrict__ W1tb,
    float* __restrict__ W2f, unsigned short* __restrict__ W2b64,
    float* __restrict__ atS, float* __restrict__ atD,
    const int* __restrict__ flags)
{
  const int fb = flags[0];
  int i = blockIdx.x * 256 + threadIdx.x;
  if (i < INDIM * HIDD) {               // W1: [512][256]
    int r = i >> 8, c = i & 255;
    float w0 = ldadapt(W1, i, fb);
    unsigned short wb = f2b(w0);
    W1b[i] = wb;                        // Bt for h4: [512 rows][256 k]
    W1tb[c * INDIM + r] = wb;           // Bt for xp1: [256 rows][512 k]
  }
  if (i < HIDD * OUTD) {                // W2: [256][32]
    int r = i >> 5, c = i & 31;
    float w0 = ldadapt(W2, i, fb);
    W2f[i] = w0;
    W2b64[r * 64 + c] = f2b(w0);        // Bt for h3: [256 rows][64 k], upper 32 zero
    W2b64[r * 64 + 32 + c] = 0;
  }
  if (i < HIDD) { atS[i] = ldadapt(aS, i, fb); atD[i] = ldadapt(aD, i, fb); }
}

// =====================================================================
// m97-structure MFMA NT GEMM + T2 bank-conflict swizzle (rule #21 form:
// linear LDS dest for global_load_lds + INVERSE-SWIZZLED GLOBAL SOURCE +
// swizzled ds_read). LDS[row][g] holds global granule g^(row&7); the
// fragment read XORs the same involution. 16-way conflict -> 2-way (free).
// AMODE:   0 = A bf16 ws buffer; 1 = A external: fb ? bf16 : f32 reg-staged
// OUTMODE: 0 = bf16 to Cb; 1 = adaptive (flags[0]) to Out+outOff
// EPI:     0 = none; 1 = ELU before store
// =====================================================================
template<int AMODE, int OUTMODE, int EPI>
__global__ __launch_bounds__(256) void gemm_nt2(
    const void* __restrict__ Av, const unsigned short* __restrict__ Bt,
    unsigned short* __restrict__ Cb, void* __restrict__ Out, size_t outOff,
    const int* __restrict__ flags, int M, int Nn, int K)
{
  __shared__ unsigned short Als[128 * 64];
  __shared__ unsigned short Bls[128 * 64];
  const int tid = threadIdx.x, lane = tid & 63, wid = tid >> 6;
  const int wr = wid >> 1, wc = wid & 1;
  const int rowBase = blockIdx.y * 128, colBase = blockIdx.x * 128;
  const int fb = flags[0];

  // staging lane geometry: row = wid*32 + i*8 + srow, LDS granule = sg.
  // row&7 == srow, so the source granule for swizzled content is sg^srow.
  const int srow = (lane >> 3), sg = lane & 7;
  const int sgx = sg ^ srow;           // inverse-swizzled source granule

  f32x4 acc[4][4] = {};

  for (int kt = 0; kt < K; kt += 64) {
    if (AMODE == 1 && !fb) {
      const float* Af = (const float*)Av;
#pragma unroll
      for (int i = 0; i < 4; ++i) {
        int row = wid * 32 + i * 8 + srow;
        int gr = rowBase + row; if (gr > M - 1) gr = M - 1;
        const float* sp = Af + (size_t)gr * K + kt + sg * 8;   // linear coalesced load
        float4 lo = *(const float4*)sp;
        float4 hi = *(const float4*)(sp + 4);
        union { unsigned short us[8]; int4 v; } cv;
        cv.us[0] = f2b(lo.x); cv.us[1] = f2b(lo.y); cv.us[2] = f2b(lo.z); cv.us[3] = f2b(lo.w);
        cv.us[4] = f2b(hi.x); cv.us[5] = f2b(hi.y); cv.us[6] = f2b(hi.z); cv.us[7] = f2b(hi.w);
        // swizzled ds_write: granule sg lands at physical slot sg^srow
        *(int4*)(Als + (wid * 4 + i) * 512 + srow * 64 + (sgx << 3)) = cv.v;
      }
    } else {
      const unsigned short* Ab = (const unsigned short*)Av;
#pragma unroll
      for (int i = 0; i < 4; ++i) {
        int row = wid * 32 + i * 8 + srow;
        int gr = rowBase + row;
        if (AMODE == 1 && gr > M - 1) gr = M - 1;   // external input: clamp
        gld16(Ab + (size_t)gr * K + kt + (sgx << 3), Als + (wid * 4 + i) * 512);
      }
    }
#pragma unroll
    for (int i = 0; i < 4; ++i) {
      int row = wid * 32 + i * 8 + srow;
      gld16(Bt + (size_t)(colBase + row) * K + kt + (sgx << 3), Bls + (wid * 4 + i) * 512);
    }
    __syncthreads();

    bf16x8 af[4], bfr[4];
#pragma unroll
    for (int ks = 0; ks < 2; ++ks) {
      int gl = ks * 4 + (lane >> 4);
      int gx = gl ^ (lane & 7);        // row&7 == lane&7 for fragment rows
#pragma unroll
      for (int mi = 0; mi < 4; ++mi) {
        int row = wr * 64 + mi * 16 + (lane & 15);
        af[mi] = *(const bf16x8*)(Als + row * 64 + (gx << 3));
      }
#pragma unroll
      for (int ni = 0; ni < 4; ++ni) {
        int row = wc * 64 + ni * 16 + (lane & 15);
        bfr[ni] = *(const bf16x8*)(Bls + row * 64 + (gx << 3));
      }
#pragma unroll
      for (int mi = 0; mi < 4; ++mi)
#pragma unroll
        for (int ni = 0; ni < 4; ++ni)
          acc[mi][ni] = __builtin_amdgcn_mfma_f32_16x16x32_bf16(af[mi], bfr[ni], acc[mi][ni], 0, 0, 0);
    }
    __syncthreads();
  }

  // C/D: col = lane&15, row = (lane>>4)*4 + reg
#pragma unroll
  for (int mi = 0; mi < 4; ++mi) {
    int r0 = rowBase + wr * 64 + mi * 16 + (lane >> 4) * 4;
#pragma unroll
    for (int ni = 0; ni < 4; ++ni) {
      int c = colBase + wc * 64 + ni * 16 + (lane & 15);
#pragma unroll
      for (int v = 0; v < 4; ++v) {
        int r = r0 + v;
        if (r < M) {
          size_t idx = (size_t)r * Nn + c;
          float x = acc[mi][ni][v];
          if (EPI) x = x > 0.f ? x : expm1f(x);
          if (OUTMODE == 0) Cb[idx] = f2b(x);
          else {
            if (fb) ((unsigned short*)Out)[outOff + idx] = f2b(x);
            else    ((float*)Out)[outOff + idx] = x;
          }
        }
      }
    }
  }
}

// ---- a_src / a_dst: one wave per node, dot(xp1_row, att); P is bf16 ----
__global__ __launch_bounds__(256) void rowdots(
    const unsigned short* __restrict__ P, const float* __restrict__ atS,
    const float* __restrict__ atD,
    float* __restrict__ asrc, float* __restrict__ adst, int N)
{
  int wave = threadIdx.x >> 6, lane = threadIdx.x & 63;
  int node = blockIdx.x * 4 + wave;
  if (node >= N) return;
  ushort4 u = *(const ushort4*)(P + (size_t)node * HIDD + lane * 4);
  float4 v = make_float4(b2f(u.x), b2f(u.y), b2f(u.z), b2f(u.w));
  float4 s = *(const float4*)(atS + lane * 4);
  float4 d = *(const float4*)(atD + lane * 4);
  float s1 = v.x * s.x + v.y * s.y + v.z * s.z + v.w * s.w;
  float s2 = v.x * d.x + v.y * d.y + v.z * d.z + v.w * d.w;
#pragma unroll
  for (int off = 32; off; off >>= 1) {
    s1 += __shfl_down(s1, off);
    s2 += __shfl_down(s2, off);
  }
  if (lane == 0) { asrc[node] = s1; adst[node] = s2; }
}

// ---- agg layer 1: wave/node, w computed at stage time, denominator in-loop ----
__global__ __launch_bounds__(256) void agg_elu2(
    const unsigned short* __restrict__ xp,
    const float* __restrict__ asrc, const float* __restrict__ adst,
    const int* __restrict__ srcP, const int* __restrict__ offs,
    unsigned short* __restrict__ hout, int N)
{
  __shared__ int   sS[4][64];
  __shared__ float sW[4][64];
  int wid = threadIdx.x >> 6, lane = threadIdx.x & 63;
  int node = blockIdx.x * 4 + wid;
  if (node >= N) return;
  const float ad = adst[node];
  int s0 = offs[node], s1 = offs[node + 1];
  float a0 = 0.f, a1 = 0.f, a2 = 0.f, a3 = 0.f, den = 0.f;
  for (int base = s0; base < s1; base += 64) {
    int cnt = s1 - base; if (cnt > 64) cnt = 64;
    if (lane < cnt) {
      int sv = srcP[base + lane];
      sS[wid][lane] = sv;
      sW[wid][lane] = edgew(asrc[sv] + ad);
    }
    asm volatile("s_waitcnt lgkmcnt(0)" ::: "memory");   // wave-local LDS RAW fence
    int j = 0;
    for (; j + 8 <= cnt; j += 8) {
      ushort4 u[8];
#pragma unroll
      for (int q = 0; q < 8; ++q)
        u[q] = *(const ushort4*)(xp + (size_t)sS[wid][j + q] * HIDD + lane * 4);
#pragma unroll
      for (int q = 0; q < 8; ++q) {
        float wv = sW[wid][j + q];
        den += wv;
        a0 += wv * b2f(u[q].x); a1 += wv * b2f(u[q].y);
        a2 += wv * b2f(u[q].z); a3 += wv * b2f(u[q].w);
      }
    }
    for (; j < cnt; ++j) {
      int   sv = sS[wid][j];
      float wv = sW[wid][j];
      den += wv;
      ushort4 u = *(const ushort4*)(xp + (size_t)sv * HIDD + lane * 4);
      a0 += wv * b2f(u.x); a1 += wv * b2f(u.y); a2 += wv * b2f(u.z); a3 += wv * b2f(u.w);
    }
  }
  float inv = 1.f / (den + 1e-16f);
  float r0 = a0 * inv, r1 = a1 * inv, r2 = a2 * inv, r3 = a3 * inv;
  r0 = r0 > 0.f ? r0 : expm1f(r0);
  r1 = r1 > 0.f ? r1 : expm1f(r1);
  r2 = r2 > 0.f ? r2 : expm1f(r2);
  r3 = r3 > 0.f ? r3 : expm1f(r3);
  ushort4 o; o.x = f2b(r0); o.y = f2b(r1); o.z = f2b(r2); o.w = f2b(r3);
  *(ushort4*)(hout + (size_t)node * HIDD + lane * 4) = o;
}

// ---- h2 = h1 @ W2 ([N,256]x[256,32]) -> adaptive out + bf16 copy ----
__global__ __launch_bounds__(256) void gemm_h2(
    const unsigned short* __restrict__ H1, const float* __restrict__ W2f,
    void* __restrict__ Out, unsigned short* __restrict__ h2b,
    const int* __restrict__ flags, int M)
{
  const int fb = flags[0];
  __shared__ float Bs[HIDD][33];
  __shared__ float As[8][HIDD];
  int tid = threadIdx.x;
  int tx = tid & 31, ty = tid >> 5;
  int row0 = blockIdx.x * 8;
#pragma unroll
  for (int j = 0; j < 32; ++j) {
    int idx = tid + 256 * j;
    Bs[idx >> 5][idx & 31] = W2f[idx];
  }
#pragma unroll
  for (int j = 0; j < 8; ++j) {
    int idx = tid + 256 * j;
    int r = idx >> 8, k = idx & 255;
    As[r][k] = (row0 + r < M) ? b2f(H1[(size_t)(row0 + r) * HIDD + k]) : 0.f;
  }
  __syncthreads();
  float acc = 0.f;
#pragma unroll 8
  for (int k = 0; k < HIDD; ++k) acc += As[ty][k] * Bs[k][tx];
  int row = row0 + ty;
  if (row < M) {
    size_t idx = (size_t)row * OUTD + tx;
    if (fb) ((unsigned short*)Out)[idx] = f2b(acc);
    else    ((float*)Out)[idx] = acc;
    h2b[idx] = f2b(acc);
  }
}

// ---- agg layer 2 on h2 [N,32] bf16 -> g2pad [N][64], w recomputed inline ----
__global__ __launch_bounds__(256) void agg_small(
    const unsigned short* __restrict__ h2b,
    const float* __restrict__ asrc, const float* __restrict__ adst,
    const int* __restrict__ srcP, const int* __restrict__ offs,
    unsigned short* __restrict__ g2pad, int N)
{
  int wid = threadIdx.x >> 6, lane = threadIdx.x & 63;
  int node = blockIdx.x * 4 + wid;
  if (node >= N) return;
  int grp = lane >> 4, cl = lane & 15;
  const float ad = adst[node];
  int s0 = offs[node], s1 = offs[node + 1];
  float a0 = 0.f, a1 = 0.f, den = 0.f;
  for (int e = s0 + grp; e < s1; e += 4) {
    int   sv = srcP[e];          // uniform across the 16-lane group (broadcast)
    float wv = edgew(asrc[sv] + ad);
    den += wv;
    ushort2 u = *(const ushort2*)(h2b + (size_t)sv * OUTD + cl * 2);
    a0 += wv * b2f(u.x);
    a1 += wv * b2f(u.y);
  }
  a0 += __shfl_xor(a0, 16); a0 += __shfl_xor(a0, 32);
  a1 += __shfl_xor(a1, 16); a1 += __shfl_xor(a1, 32);
  den += __shfl_xor(den, 16); den += __shfl_xor(den, 32);
  if (grp == 0) {
    float inv = 1.f / (den + 1e-16f);
    ushort2 o; o.x = f2b(a0 * inv); o.y = f2b(a1 * inv);
    *(ushort2*)(g2pad + (size_t)node * 64 + cl * 2) = o;
  } else if (grp == 1) {
    *(ushort2*)(g2pad + (size_t)node * 64 + 32 + cl * 2) = make_ushort2(0, 0);  // K-pad
  }
}

extern "C" void kernel_launch(void* const* d_in, const int* in_sizes, int n_in,
                              void* d_out, int out_size, void* d_ws, size_t ws_size,
                              hipStream_t stream)
{
  const void*         feat = d_in[0];
  const unsigned int* eidx = (const unsigned int*)d_in[1];
  const void*         W1   = d_in[2];
  const void*         W2   = d_in[3];
  const void*         aS   = d_in[4];
  const void*         aD   = d_in[5];

  const int N = in_sizes[0] / INDIM;
  const int E = in_sizes[1] / 2;
  const int M_pad = ((N + 127) / 128) * 128;
  const int nslab = (N + SLABN - 1) / SLABN;   // 49 for N=100000; must be <= 64
  const int npb = (E + PCH - 1) / PCH;

  char* w = (char*)d_ws;
  auto alloc = [&](size_t bytes) -> char* {
    char* p = w; w += (bytes + 255) & ~(size_t)255; return p;
  };
  unsigned short* H     = (unsigned short*)alloc((size_t)M_pad * HIDD * 2);  // h1 / h3
  unsigned short* P     = (unsigned short*)alloc((size_t)M_pad * HIDD * 2);  // xp1
  unsigned short* h2b   = (unsigned short*)alloc((size_t)N * OUTD * 2);      // h2 bf16
  unsigned short* g2pad = (unsigned short*)alloc((size_t)M_pad * 64 * 2);    // agg(h2), K-padded
  float* asrc = (float*)alloc((size_t)N * 4);
  float* adst = (float*)alloc((size_t)N * 4);
  int*   srcP = (int*)alloc((size_t)E * 4);     // CSR-ordered edge src
  uint2* part = (uint2*)alloc((size_t)E * 8);   // slab-partitioned (src,dst)
  int*   offs = (int*)alloc((size_t)(N + 1) * 4);
  int*   bcnt = (int*)alloc((size_t)npb * 64 * 4);
  int*   slabOff = (int*)alloc(65 * 4);
  unsigned short* W1b   = (unsigned short*)alloc((size_t)INDIM * HIDD * 2); // [512][256]
  unsigned short* W1tb  = (unsigned short*)alloc((size_t)INDIM * HIDD * 2); // [256][512]
  unsigned short* W2b64 = (unsigned short*)alloc((size_t)HIDD * 64 * 2);    // [256][64]
  float* W2f  = (float*)alloc((size_t)HIDD * OUTD * 4);
  float* atS  = (float*)alloc((size_t)HIDD * 4);
  float* atD  = (float*)alloc((size_t)HIDD * 4);
  int*   flags = (int*)alloc(64);

  probe_kernel<<<1, 256, 0, stream>>>((const unsigned int*)feat, eidx, flags);

  // CSR build: radix by dst-slab, then slab-local CSR in LDS (no global atomics)
  cnt_kernel<<<npb, 256, 0, stream>>>(eidx, bcnt, E, flags);
  bscan_kernel<<<1, 64, 0, stream>>>(bcnt, slabOff, npb);
  scat_kernel<<<npb, 256, 0, stream>>>(eidx, bcnt, slabOff, part, E, flags);
  slabcsr_kernel<<<nslab, 256, 0, stream>>>(part, slabOff, offs, srcP, N, nslab);

  prep_weights<<<512, 256, 0, stream>>>(W1, W2, aS, aD, W1b, W1tb, W2f, W2b64, atS, atD, flags);

  const int mb = (N + 127) / 128;

  // xp1 = feat @ W1 (f32 A converted in staging, or bf16 gld16 per flag)
  gemm_nt2<1, 0, 0><<<dim3(HIDD / 128, mb), 256, 0, stream>>>(
      feat, W1tb, P, nullptr, 0, flags, N, HIDD, INDIM);

  rowdots<<<(N + 3) / 4, 256, 0, stream>>>(P, atS, atD, asrc, adst, N);

  // GAT layer 1: h1 = elu(agg(xp1)/denom)
  agg_elu2<<<(N + 3) / 4, 256, 0, stream>>>(P, asrc, adst, srcP, offs, H, N);

  // h2 = h1 @ W2 -> output 0 (+ bf16 copy for layer-2 agg)
  gemm_h2<<<(N + 7) / 8, 256, 0, stream>>>(H, W2f, d_out, h2b, flags, N);

  // GAT layer 2, commuted: g2 = agg(h2) [N,32->64pad]
  agg_small<<<(N + 3) / 4, 256, 0, stream>>>(h2b, asrc, adst, srcP, offs, g2pad, N);

  // h3 = elu(g2 @ W2^T) via MFMA GEMM
  gemm_nt2<0, 0, 1><<<dim3(HIDD / 128, mb), 256, 0, stream>>>(
      g2pad, W2b64, H, nullptr, 0, flags, N, HIDD, 64);

  // h4 = h3 @ W1^T -> output 1 (adaptive)
  gemm_nt2<0, 1, 0><<<dim3(INDIM / 128, mb), 256, 0, stream>>>(
      H, W1b, nullptr, d_out, (size_t)N * OUTD, flags, N, INDIM, HIDD);
}

// Round 12
// 699.568 us; speedup vs baseline: 1.1694x; 1.0073x over previous
//
#include <hip/hip_runtime.h>
#include <cstdint>
#include <cstddef>

#define INDIM 512
#define HIDD  256
#define OUTD  32
#define PCH   4096      // edges per radix block
#define SLABN 2048      // nodes per slab (shift 11); nslab <= 64

typedef __attribute__((ext_vector_type(4))) float f32x4;
typedef __attribute__((ext_vector_type(8))) short bf16x8;

// ---- bf16 <-> f32 helpers ----
static inline __device__ float b2f(unsigned short u) {
  union { float f; unsigned int i; } v; v.i = ((unsigned int)u) << 16; return v.f;
}
static inline __device__ unsigned short f2b(float f) {
  union { float f; unsigned int i; } v; v.f = f;
  unsigned int x = v.i;
  x += 0x7fffu + ((x >> 16) & 1u);   // round-to-nearest-even
  return (unsigned short)(x >> 16);
}

// edge weight: exp(sigmoid(x)) — SAME formula in both agg kernels
static inline __device__ float edgew(float x) {
  float al = 1.f / (1.f + __expf(-x));
  return __expf(al);
}

// async global->LDS, 16B per lane. LDS dest = wave-uniform base + lane*16.
static __device__ __forceinline__ void gld16(const unsigned short* g, unsigned short* l) {
  __builtin_amdgcn_global_load_lds(
      (const __attribute__((address_space(1))) void*)g,
      (__attribute__((address_space(3))) void*)l, 16, 0, 0);
}

// ---- runtime dtype probe ----
__global__ __launch_bounds__(256) void probe_kernel(
    const unsigned int* __restrict__ feat, const unsigned int* __restrict__ eidx,
    int* __restrict__ flags)
{
  int t = threadIdx.x;
  __shared__ int cnt, oddnz;
  if (t == 0) { cnt = 0; oddnz = 0; }
  __syncthreads();
  unsigned int w = feat[t];
  unsigned short lo = (unsigned short)(w & 0xFFFFu);
  int e = (lo >> 7) & 0xFF;
  int plausible = ((lo & 0x7FFF) == 0) || (e >= 0x60 && e <= 0x9F);
  atomicAdd(&cnt, plausible);
  if (t & 1) { if (eidx[t] != 0u) atomicAdd(&oddnz, 1); }
  __syncthreads();
  if (t == 0) { flags[0] = (cnt >= 192) ? 1 : 0; flags[1] = (oddnz == 0) ? 1 : 0; }
}

// ---- radix pass A: per-block slab counts (LDS hist, plain global writes) ----
__global__ __launch_bounds__(256) void cnt_kernel(
    const unsigned int* __restrict__ eidx, int* __restrict__ bcnt,
    int E, const int* __restrict__ flags)
{
  __shared__ int hist[64];
  int t = threadIdx.x;
  if (t < 64) hist[t] = 0;
  __syncthreads();
  int e0 = blockIdx.x * PCH;
  const int i64 = flags[1];
  for (int i = t; i < PCH; i += 256) {
    int e = e0 + i; if (e >= E) break;
    int d = i64 ? (int)eidx[2 * ((size_t)E + e)] : (int)eidx[(size_t)E + e];
    atomicAdd(&hist[d >> 11], 1);
  }
  __syncthreads();
  if (t < 64) bcnt[blockIdx.x * 64 + t] = hist[t];
}

// ---- radix pass B: bcnt -> within-slab block prefixes; slabOff exclusive scan ----
__global__ __launch_bounds__(64) void bscan_kernel(
    int* __restrict__ bcnt, int* __restrict__ slabOff, int npb)
{
  int t = threadIdx.x;           // lane = slab
  int run = 0;
  for (int b = 0; b < npb; ++b) {
    int v = bcnt[b * 64 + t];
    bcnt[b * 64 + t] = run;      // within-slab prefix
    run += v;
  }
  int inc = run;
#pragma unroll
  for (int o = 1; o < 64; o <<= 1) {
    int u = __shfl_up(inc, o);
    if (t >= o) inc += u;
  }
  slabOff[t] = inc - run;        // exclusive
  if (t == 63) slabOff[64] = inc;   // = E
}

// ---- radix pass C: scatter (src,dst) into slab-contiguous part[] ----
__global__ __launch_bounds__(256) void scat_kernel(
    const unsigned int* __restrict__ eidx, const int* __restrict__ bcnt,
    const int* __restrict__ slabOff, uint2* __restrict__ part,
    int E, const int* __restrict__ flags)
{
  __shared__ int cur[64];
  int t = threadIdx.x;
  if (t < 64) cur[t] = slabOff[t] + bcnt[blockIdx.x * 64 + t];
  __syncthreads();
  int e0 = blockIdx.x * PCH;
  const int i64 = flags[1];
  for (int i = t; i < PCH; i += 256) {
    int e = e0 + i; if (e >= E) break;
    int s, d;
    if (i64) { s = (int)eidx[2 * (size_t)e]; d = (int)eidx[2 * ((size_t)E + e)]; }
    else     { s = (int)eidx[e];             d = (int)eidx[(size_t)E + e]; }
    int pos = atomicAdd(&cur[d >> 11], 1);
    part[pos] = make_uint2((unsigned)s, (unsigned)d);
  }
}

// ---- radix pass D: per-slab CSR build fully in LDS (deg, scan, fill) ----
__global__ __launch_bounds__(256) void slabcsr_kernel(
    const uint2* __restrict__ part, const int* __restrict__ slabOff,
    int* __restrict__ offs, int* __restrict__ srcP, int N, int nslab)
{
  __shared__ int deg[SLABN];
  __shared__ int wsum[4];
  int sl = blockIdx.x, t = threadIdx.x;
  int n0 = sl << 11;
  int nn = N - n0; if (nn > SLABN) nn = SLABN;
  int s0 = slabOff[sl], s1 = slabOff[sl + 1];
  for (int i = t; i < SLABN; i += 256) deg[i] = 0;
  __syncthreads();
  for (int i = s0 + t; i < s1; i += 256)
    atomicAdd(&deg[(int)part[i].y - n0], 1);
  __syncthreads();
  // block-wide exclusive scan of deg[0..SLABN): 8 elems/thread
  int loc[8]; int bi = t * 8; int s = 0;
#pragma unroll
  for (int j = 0; j < 8; ++j) { loc[j] = deg[bi + j]; s += loc[j]; }
  int ws = s;
#pragma unroll
  for (int o = 1; o < 64; o <<= 1) {
    int u = __shfl_up(ws, o);
    if ((t & 63) >= o) ws += u;
  }
  if ((t & 63) == 63) wsum[t >> 6] = ws;
  __syncthreads();
  if (t < 4) {
    int v = wsum[t], inc = v;
#pragma unroll
    for (int o = 1; o < 4; o <<= 1) {
      int u = __shfl_up(inc, o);
      if (t >= o) inc += u;
    }
    wsum[t] = inc - v;
  }
  __syncthreads();
  int run = wsum[t >> 6] + (ws - s);   // thread-exclusive base
#pragma unroll
  for (int j = 0; j < 8; ++j) {
    int idx = bi + j;
    int v = loc[j];
    deg[idx] = run;                    // local cursor init
    if (idx < nn) offs[n0 + idx] = s0 + run;
    run += v;
  }
  __syncthreads();
  for (int i = s0 + t; i < s1; i += 256) {
    uint2 p = part[i];
    int pos = s0 + atomicAdd(&deg[(int)p.y - n0], 1);
    srcP[pos] = (int)p.x;
  }
  if (sl == nslab - 1 && t == 0) offs[N] = s1;
}

static inline __device__ float ldadapt(const void* p, size_t i, int isbf) {
  return isbf ? b2f(((const unsigned short*)p)[i]) : ((const float*)p)[i];
}

// ---- weight prep: W1b, W1tb, W2f, W2b64 ([256][64] bf16, zero-padded K), att ----
__global__ __launch_bounds__(256) void prep_weights(
    const void* __restrict__ W1, const void* __restrict__ W2,
    const void* __restrict__ aS, const void* __restrict__ aD,
    unsigned short* __restrict__ W1b, unsigned short* __restrict__ W1tb,
    float* __restrict__ W2f, unsigned short* __restrict__ W2b64,
    float* __restrict__ atS, float* __restrict__ atD,
    const int* __restrict__ flags)
{
  const int fb = flags[0];
  int i = blockIdx.x * 256 + threadIdx.x;
  if (i < INDIM * HIDD) {               // W1: [512][256]
    int r = i >> 8, c = i & 255;
    float w0 = ldadapt(W1, i, fb);
    unsigned short wb = f2b(w0);
    W1b[i] = wb;                        // Bt for h4: [512 rows][256 k]
    W1tb[c * INDIM + r] = wb;           // Bt for xp1: [256 rows][512 k]
  }
  if (i < HIDD * OUTD) {                // W2: [256][32]
    int r = i >> 5, c = i & 31;
    float w0 = ldadapt(W2, i, fb);
    W2f[i] = w0;
    W2b64[r * 64 + c] = f2b(w0);        // Bt for h3: [256 rows][64 k], upper 32 zero
    W2b64[r * 64 + 32 + c] = 0;
  }
  if (i < HIDD) { atS[i] = ldadapt(aS, i, fb); atD[i] = ldadapt(aD, i, fb); }
}

// =====================================================================
// m97-structure MFMA NT GEMM + T2 swizzle (rule #21 form: linear LDS dest
// for global_load_lds + inverse-swizzled GLOBAL source + swizzled ds_read).
// AMODE:   0 = A bf16 ws buffer; 1 = A external: fb ? bf16 : f32 reg-staged
// OUTMODE: 0 = bf16 to Cb; 1 = adaptive (flags[0]) to Out+outOff
// EPI:     0 = none; 1 = ELU before store
// =====================================================================
template<int AMODE, int OUTMODE, int EPI>
__global__ __launch_bounds__(256) void gemm_nt2(
    const void* __restrict__ Av, const unsigned short* __restrict__ Bt,
    unsigned short* __restrict__ Cb, void* __restrict__ Out, size_t outOff,
    const int* __restrict__ flags, int M, int Nn, int K)
{
  __shared__ unsigned short Als[128 * 64];
  __shared__ unsigned short Bls[128 * 64];
  const int tid = threadIdx.x, lane = tid & 63, wid = tid >> 6;
  const int wr = wid >> 1, wc = wid & 1;
  const int rowBase = blockIdx.y * 128, colBase = blockIdx.x * 128;
  const int fb = flags[0];

  const int srow = (lane >> 3), sg = lane & 7;
  const int sgx = sg ^ srow;           // inverse-swizzled source granule

  f32x4 acc[4][4] = {};

  for (int kt = 0; kt < K; kt += 64) {
    if (AMODE == 1 && !fb) {
      const float* Af = (const float*)Av;
#pragma unroll
      for (int i = 0; i < 4; ++i) {
        int row = wid * 32 + i * 8 + srow;
        int gr = rowBase + row; if (gr > M - 1) gr = M - 1;
        const float* sp = Af + (size_t)gr * K + kt + sg * 8;   // linear coalesced load
        float4 lo = *(const float4*)sp;
        float4 hi = *(const float4*)(sp + 4);
        union { unsigned short us[8]; int4 v; } cv;
        cv.us[0] = f2b(lo.x); cv.us[1] = f2b(lo.y); cv.us[2] = f2b(lo.z); cv.us[3] = f2b(lo.w);
        cv.us[4] = f2b(hi.x); cv.us[5] = f2b(hi.y); cv.us[6] = f2b(hi.z); cv.us[7] = f2b(hi.w);
        *(int4*)(Als + (wid * 4 + i) * 512 + srow * 64 + (sgx << 3)) = cv.v;
      }
    } else {
      const unsigned short* Ab = (const unsigned short*)Av;
#pragma unroll
      for (int i = 0; i < 4; ++i) {
        int row = wid * 32 + i * 8 + srow;
        int gr = rowBase + row;
        if (AMODE == 1 && gr > M - 1) gr = M - 1;   // external input: clamp
        gld16(Ab + (size_t)gr * K + kt + (sgx << 3), Als + (wid * 4 + i) * 512);
      }
    }
#pragma unroll
    for (int i = 0; i < 4; ++i) {
      int row = wid * 32 + i * 8 + srow;
      gld16(Bt + (size_t)(colBase + row) * K + kt + (sgx << 3), Bls + (wid * 4 + i) * 512);
    }
    __syncthreads();

    bf16x8 af[4], bfr[4];
#pragma unroll
    for (int ks = 0; ks < 2; ++ks) {
      int gl = ks * 4 + (lane >> 4);
      int gx = gl ^ (lane & 7);        // row&7 == lane&7 for fragment rows
#pragma unroll
      for (int mi = 0; mi < 4; ++mi) {
        int row = wr * 64 + mi * 16 + (lane & 15);
        af[mi] = *(const bf16x8*)(Als + row * 64 + (gx << 3));
      }
#pragma unroll
      for (int ni = 0; ni < 4; ++ni) {
        int row = wc * 64 + ni * 16 + (lane & 15);
        bfr[ni] = *(const bf16x8*)(Bls + row * 64 + (gx << 3));
      }
#pragma unroll
      for (int mi = 0; mi < 4; ++mi)
#pragma unroll
        for (int ni = 0; ni < 4; ++ni)
          acc[mi][ni] = __builtin_amdgcn_mfma_f32_16x16x32_bf16(af[mi], bfr[ni], acc[mi][ni], 0, 0, 0);
    }
    __syncthreads();
  }

  // C/D: col = lane&15, row = (lane>>4)*4 + reg
#pragma unroll
  for (int mi = 0; mi < 4; ++mi) {
    int r0 = rowBase + wr * 64 + mi * 16 + (lane >> 4) * 4;
#pragma unroll
    for (int ni = 0; ni < 4; ++ni) {
      int c = colBase + wc * 64 + ni * 16 + (lane & 15);
#pragma unroll
      for (int v = 0; v < 4; ++v) {
        int r = r0 + v;
        if (r < M) {
          size_t idx = (size_t)r * Nn + c;
          float x = acc[mi][ni][v];
          if (EPI) x = x > 0.f ? x : expm1f(x);
          if (OUTMODE == 0) Cb[idx] = f2b(x);
          else {
            if (fb) ((unsigned short*)Out)[outOff + idx] = f2b(x);
            else    ((float*)Out)[outOff + idx] = x;
          }
        }
      }
    }
  }
}

// ---- a_src / a_dst: one wave per node, dot(xp1_row, att); P is bf16 ----
__global__ __launch_bounds__(256) void rowdots(
    const unsigned short* __restrict__ P, const float* __restrict__ atS,
    const float* __restrict__ atD,
    float* __restrict__ asrc, float* __restrict__ adst, int N)
{
  int wave = threadIdx.x >> 6, lane = threadIdx.x & 63;
  int node = blockIdx.x * 4 + wave;
  if (node >= N) return;
  ushort4 u = *(const ushort4*)(P + (size_t)node * HIDD + lane * 4);
  float4 v = make_float4(b2f(u.x), b2f(u.y), b2f(u.z), b2f(u.w));
  float4 s = *(const float4*)(atS + lane * 4);
  float4 d = *(const float4*)(atD + lane * 4);
  float s1 = v.x * s.x + v.y * s.y + v.z * s.z + v.w * s.w;
  float s2 = v.x * d.x + v.y * d.y + v.z * d.z + v.w * d.w;
#pragma unroll
  for (int off = 32; off; off >>= 1) {
    s1 += __shfl_down(s1, off);
    s2 += __shfl_down(s2, off);
  }
  if (lane == 0) { asrc[node] = s1; adst[node] = s2; }
}

// ---- agg layer 1: wave/node, 16 gathers in flight, denominator in-loop ----
__global__ __launch_bounds__(256) void agg_elu2(
    const unsigned short* __restrict__ xp,
    const float* __restrict__ asrc, const float* __restrict__ adst,
    const int* __restrict__ srcP, const int* __restrict__ offs,
    unsigned short* __restrict__ hout, int N)
{
  __shared__ int   sS[4][64];
  __shared__ float sW[4][64];
  int wid = threadIdx.x >> 6, lane = threadIdx.x & 63;
  int node = blockIdx.x * 4 + wid;
  if (node >= N) return;
  const float ad = adst[node];
  int s0 = offs[node], s1 = offs[node + 1];
  float a0 = 0.f, a1 = 0.f, a2 = 0.f, a3 = 0.f, den = 0.f;
  for (int base = s0; base < s1; base += 64) {
    int cnt = s1 - base; if (cnt > 64) cnt = 64;
    if (lane < cnt) {
      int sv = srcP[base + lane];
      sS[wid][lane] = sv;
      sW[wid][lane] = edgew(asrc[sv] + ad);
    }
    asm volatile("s_waitcnt lgkmcnt(0)" ::: "memory");   // wave-local LDS RAW fence
    int j = 0;
    for (; j + 16 <= cnt; j += 16) {          // 16 gathers in flight
      ushort4 u[16];
#pragma unroll
      for (int q = 0; q < 16; ++q)
        u[q] = *(const ushort4*)(xp + (size_t)sS[wid][j + q] * HIDD + lane * 4);
#pragma unroll
      for (int q = 0; q < 16; ++q) {
        float wv = sW[wid][j + q];
        den += wv;
        a0 += wv * b2f(u[q].x); a1 += wv * b2f(u[q].y);
        a2 += wv * b2f(u[q].z); a3 += wv * b2f(u[q].w);
      }
    }
    for (; j + 8 <= cnt; j += 8) {
      ushort4 u[8];
#pragma unroll
      for (int q = 0; q < 8; ++q)
        u[q] = *(const ushort4*)(xp + (size_t)sS[wid][j + q] * HIDD + lane * 4);
#pragma unroll
      for (int q = 0; q < 8; ++q) {
        float wv = sW[wid][j + q];
        den += wv;
        a0 += wv * b2f(u[q].x); a1 += wv * b2f(u[q].y);
        a2 += wv * b2f(u[q].z); a3 += wv * b2f(u[q].w);
      }
    }
    for (; j < cnt; ++j) {
      int   sv = sS[wid][j];
      float wv = sW[wid][j];
      den += wv;
      ushort4 u = *(const ushort4*)(xp + (size_t)sv * HIDD + lane * 4);
      a0 += wv * b2f(u.x); a1 += wv * b2f(u.y); a2 += wv * b2f(u.z); a3 += wv * b2f(u.w);
    }
  }
  float inv = 1.f / (den + 1e-16f);
  float r0 = a0 * inv, r1 = a1 * inv, r2 = a2 * inv, r3 = a3 * inv;
  r0 = r0 > 0.f ? r0 : expm1f(r0);
  r1 = r1 > 0.f ? r1 : expm1f(r1);
  r2 = r2 > 0.f ? r2 : expm1f(r2);
  r3 = r3 > 0.f ? r3 : expm1f(r3);
  ushort4 o; o.x = f2b(r0); o.y = f2b(r1); o.z = f2b(r2); o.w = f2b(r3);
  *(ushort4*)(hout + (size_t)node * HIDD + lane * 4) = o;
}

// ---- h2 = h1 @ W2 ([N,256]x[256,32]) -> adaptive out + bf16 copy ----
// staging vectorized: one ushort8 (16B) H1 load per thread, float4 W2 loads
__global__ __launch_bounds__(256) void gemm_h2(
    const unsigned short* __restrict__ H1, const float* __restrict__ W2f,
    void* __restrict__ Out, unsigned short* __restrict__ h2b,
    const int* __restrict__ flags, int M)
{
  const int fb = flags[0];
  __shared__ float Bs[HIDD][33];
  __shared__ float As[8][HIDD];
  int tid = threadIdx.x;
  int tx = tid & 31, ty = tid >> 5;
  int row0 = blockIdx.x * 8;
#pragma unroll
  for (int j = 0; j < 8; ++j) {            // W2 (256x32 f32) via float4
    int idx4 = tid + 256 * j;              // 2048 float4s
    float4 v = *(const float4*)(W2f + idx4 * 4);
    int k = idx4 >> 3, c = (idx4 & 7) * 4;
    Bs[k][c] = v.x; Bs[k][c + 1] = v.y; Bs[k][c + 2] = v.z; Bs[k][c + 3] = v.w;
  }
  {
    int flat = tid * 8;                    // 8 rows x 256 = 2048 bf16, 16B/thread
    int r = flat >> 8, k = flat & 255;
    int gr = row0 + r;
    if (gr < M) {
      ushort4 lo = *(const ushort4*)(H1 + (size_t)gr * HIDD + k);
      ushort4 hi = *(const ushort4*)(H1 + (size_t)gr * HIDD + k + 4);
      As[r][k] = b2f(lo.x); As[r][k + 1] = b2f(lo.y); As[r][k + 2] = b2f(lo.z); As[r][k + 3] = b2f(lo.w);
      As[r][k + 4] = b2f(hi.x); As[r][k + 5] = b2f(hi.y); As[r][k + 6] = b2f(hi.z); As[r][k + 7] = b2f(hi.w);
    } else {
#pragma unroll
      for (int q = 0; q < 8; ++q) As[r][k + q] = 0.f;
    }
  }
  __syncthreads();
  float acc = 0.f;
#pragma unroll 8
  for (int k = 0; k < HIDD; ++k) acc += As[ty][k] * Bs[k][tx];
  int row = row0 + ty;
  if (row < M) {
    size_t idx = (size_t)row * OUTD + tx;
    if (fb) ((unsigned short*)Out)[idx] = f2b(acc);
    else    ((float*)Out)[idx] = acc;
    h2b[idx] = f2b(acc);
  }
}

// ---- agg layer 2 on h2 [N,32] bf16 -> g2pad [N][64], w recomputed inline ----
__global__ __launch_bounds__(256) void agg_small(
    const unsigned short* __restrict__ h2b,
    const float* __restrict__ asrc, const float* __restrict__ adst,
    const int* __restrict__ srcP, const int* __restrict__ offs,
    unsigned short* __restrict__ g2pad, int N)
{
  int wid = threadIdx.x >> 6, lane = threadIdx.x & 63;
  int node = blockIdx.x * 4 + wid;
  if (node >= N) return;
  int grp = lane >> 4, cl = lane & 15;
  const float ad = adst[node];
  int s0 = offs[node], s1 = offs[node + 1];
  float a0 = 0.f, a1 = 0.f, den = 0.f;
  for (int e = s0 + grp; e < s1; e += 4) {
    int   sv = srcP[e];          // uniform across the 16-lane group (broadcast)
    float wv = edgew(asrc[sv] + ad);
    den += wv;
    ushort2 u = *(const ushort2*)(h2b + (size_t)sv * OUTD + cl * 2);
    a0 += wv * b2f(u.x);
    a1 += wv * b2f(u.y);
  }
  a0 += __shfl_xor(a0, 16); a0 += __shfl_xor(a0, 32);
  a1 += __shfl_xor(a1, 16); a1 += __shfl_xor(a1, 32);
  den += __shfl_xor(den, 16); den += __shfl_xor(den, 32);
  if (grp == 0) {
    float inv = 1.f / (den + 1e-16f);
    ushort2 o; o.x = f2b(a0 * inv); o.y = f2b(a1 * inv);
    *(ushort2*)(g2pad + (size_t)node * 64 + cl * 2) = o;
  } else if (grp == 1) {
    *(ushort2*)(g2pad + (size_t)node * 64 + 32 + cl * 2) = make_ushort2(0, 0);  // K-pad
  }
}

extern "C" void kernel_launch(void* const* d_in, const int* in_sizes, int n_in,
                              void* d_out, int out_size, void* d_ws, size_t ws_size,
                              hipStream_t stream)
{
  const void*         feat = d_in[0];
  const unsigned int* eidx = (const unsigned int*)d_in[1];
  const void*         W1   = d_in[2];
  const void*         W2   = d_in[3];
  const void*         aS   = d_in[4];
  const void*         aD   = d_in[5];

  const int N = in_sizes[0] / INDIM;
  const int E = in_sizes[1] / 2;
  const int M_pad = ((N + 127) / 128) * 128;
  const int nslab = (N + SLABN - 1) / SLABN;   // 49 for N=100000; must be <= 64
  const int npb = (E + PCH - 1) / PCH;

  char* w = (char*)d_ws;
  auto alloc = [&](size_t bytes) -> char* {
    char* p = w; w += (bytes + 255) & ~(size_t)255; return p;
  };
  unsigned short* H     = (unsigned short*)alloc((size_t)M_pad * HIDD * 2);  // h1 / h3
  unsigned short* P     = (unsigned short*)alloc((size_t)M_pad * HIDD * 2);  // xp1
  unsigned short* h2b   = (unsigned short*)alloc((size_t)N * OUTD * 2);      // h2 bf16
  unsigned short* g2pad = (unsigned short*)alloc((size_t)M_pad * 64 * 2);    // agg(h2), K-padded
  float* asrc = (float*)alloc((size_t)N * 4);
  float* adst = (float*)alloc((size_t)N * 4);
  int*   srcP = (int*)alloc((size_t)E * 4);     // CSR-ordered edge src
  uint2* part = (uint2*)alloc((size_t)E * 8);   // slab-partitioned (src,dst)
  int*   offs = (int*)alloc((size_t)(N + 1) * 4);
  int*   bcnt = (int*)alloc((size_t)npb * 64 * 4);
  int*   slabOff = (int*)alloc(65 * 4);
  unsigned short* W1b   = (unsigned short*)alloc((size_t)INDIM * HIDD * 2); // [512][256]
  unsigned short* W1tb  = (unsigned short*)alloc((size_t)INDIM * HIDD * 2); // [256][512]
  unsigned short* W2b64 = (unsigned short*)alloc((size_t)HIDD * 64 * 2);    // [256][64]
  float* W2f  = (float*)alloc((size_t)HIDD * OUTD * 4);
  float* atS  = (float*)alloc((size_t)HIDD * 4);
  float* atD  = (float*)alloc((size_t)HIDD * 4);
  int*   flags = (int*)alloc(64);

  probe_kernel<<<1, 256, 0, stream>>>((const unsigned int*)feat, eidx, flags);

  // CSR build: radix by dst-slab, then slab-local CSR in LDS (no global atomics)
  cnt_kernel<<<npb, 256, 0, stream>>>(eidx, bcnt, E, flags);
  bscan_kernel<<<1, 64, 0, stream>>>(bcnt, slabOff, npb);
  scat_kernel<<<npb, 256, 0, stream>>>(eidx, bcnt, slabOff, part, E, flags);
  slabcsr_kernel<<<nslab, 256, 0, stream>>>(part, slabOff, offs, srcP, N, nslab);

  prep_weights<<<512, 256, 0, stream>>>(W1, W2, aS, aD, W1b, W1tb, W2f, W2b64, atS, atD, flags);

  const int mb = (N + 127) / 128;

  // xp1 = feat @ W1 (f32 A converted in staging, or bf16 gld16 per flag)
  gemm_nt2<1, 0, 0><<<dim3(HIDD / 128, mb), 256, 0, stream>>>(
      feat, W1tb, P, nullptr, 0, flags, N, HIDD, INDIM);

  rowdots<<<(N + 3) / 4, 256, 0, stream>>>(P, atS, atD, asrc, adst, N);

  // GAT layer 1: h1 = elu(agg(xp1)/denom)
  agg_elu2<<<(N + 3) / 4, 256, 0, stream>>>(P, asrc, adst, srcP, offs, H, N);

  // h2 = h1 @ W2 -> output 0 (+ bf16 copy for layer-2 agg)
  gemm_h2<<<(N + 7) / 8, 256, 0, stream>>>(H, W2f, d_out, h2b, flags, N);

  // GAT layer 2, commuted: g2 = agg(h2) [N,32->64pad]
  agg_small<<<(N + 3) / 4, 256, 0, stream>>>(h2b, asrc, adst, srcP, offs, g2pad, N);

  // h3 = elu(g2 @ W2^T) via MFMA GEMM
  gemm_nt2<0, 0, 1><<<dim3(HIDD / 128, mb), 256, 0, stream>>>(
      g2pad, W2b64, H, nullptr, 0, flags, N, HIDD, 64);

  // h4 = h3 @ W1^T -> output 1 (adaptive)
  gemm_nt2<0, 1, 0><<<dim3(INDIM / 128, mb), 256, 0, stream>>>(
      H, W1b, nullptr, d_out, (size_t)N * OUTD, flags, N, INDIM, HIDD);
}

// Round 13
// 657.873 us; speedup vs baseline: 1.2436x; 1.0634x over previous
//
#include <hip/hip_runtime.h>
#include <cstdint>
#include <cstddef>

#define INDIM 512
#define HIDD  256
#define OUTD  32
#define PCH   4096      // edges per radix block
#define SHIFT 9
#define SLABN 512       // nodes per slab; nslab <= 256

typedef __attribute__((ext_vector_type(4))) float f32x4;
typedef __attribute__((ext_vector_type(8))) short bf16x8;

// ---- bf16 <-> f32 helpers ----
static inline __device__ float b2f(unsigned short u) {
  union { float f; unsigned int i; } v; v.i = ((unsigned int)u) << 16; return v.f;
}
static inline __device__ unsigned short f2b(float f) {
  union { float f; unsigned int i; } v; v.f = f;
  unsigned int x = v.i;
  x += 0x7fffu + ((x >> 16) & 1u);   // round-to-nearest-even
  return (unsigned short)(x >> 16);
}

// edge weight: exp(sigmoid(x)) — SAME formula in both agg kernels
static inline __device__ float edgew(float x) {
  float al = 1.f / (1.f + __expf(-x));
  return __expf(al);
}

// async global->LDS, 16B per lane. LDS dest = wave-uniform base + lane*16.
static __device__ __forceinline__ void gld16(const unsigned short* g, unsigned short* l) {
  __builtin_amdgcn_global_load_lds(
      (const __attribute__((address_space(1))) void*)g,
      (__attribute__((address_space(3))) void*)l, 16, 0, 0);
}

// ---- runtime dtype probe ----
__global__ __launch_bounds__(256) void probe_kernel(
    const unsigned int* __restrict__ feat, const unsigned int* __restrict__ eidx,
    int* __restrict__ flags)
{
  int t = threadIdx.x;
  __shared__ int cnt, oddnz;
  if (t == 0) { cnt = 0; oddnz = 0; }
  __syncthreads();
  unsigned int w = feat[t];
  unsigned short lo = (unsigned short)(w & 0xFFFFu);
  int e = (lo >> 7) & 0xFF;
  int plausible = ((lo & 0x7FFF) == 0) || (e >= 0x60 && e <= 0x9F);
  atomicAdd(&cnt, plausible);
  if (t & 1) { if (eidx[t] != 0u) atomicAdd(&oddnz, 1); }
  __syncthreads();
  if (t == 0) { flags[0] = (cnt >= 192) ? 1 : 0; flags[1] = (oddnz == 0) ? 1 : 0; }
}

// ---- radix pass A: per-block slab counts (LDS hist, plain global writes) ----
__global__ __launch_bounds__(256) void cnt_kernel(
    const unsigned int* __restrict__ eidx, int* __restrict__ bcnt,
    int E, const int* __restrict__ flags)
{
  __shared__ int hist[256];
  int t = threadIdx.x;
  hist[t] = 0;
  __syncthreads();
  int e0 = blockIdx.x * PCH;
  const int i64 = flags[1];
  for (int i = t; i < PCH; i += 256) {
    int e = e0 + i; if (e >= E) break;
    int d = i64 ? (int)eidx[2 * ((size_t)E + e)] : (int)eidx[(size_t)E + e];
    atomicAdd(&hist[d >> SHIFT], 1);
  }
  __syncthreads();
  bcnt[blockIdx.x * 256 + t] = hist[t];
}

// ---- radix pass B: bcnt -> within-slab block prefixes; slabOff excl scan ----
// 256 threads, lane t owns slab t; coalesced 1KB loads per iteration.
__global__ __launch_bounds__(256) void bscan_kernel(
    int* __restrict__ bcnt, int* __restrict__ slabOff, int npb)
{
  __shared__ int wsum[4];
  int t = threadIdx.x, lane = t & 63, wv = t >> 6;
  int run = 0;
  for (int b = 0; b < npb; ++b) {
    int v = bcnt[b * 256 + t];
    bcnt[b * 256 + t] = run;     // within-slab prefix
    run += v;
  }
  int inc = run;
#pragma unroll
  for (int o = 1; o < 64; o <<= 1) {
    int u = __shfl_up(inc, o);
    if (lane >= o) inc += u;
  }
  if (lane == 63) wsum[wv] = inc;
  __syncthreads();
  if (t < 4) {
    int v = wsum[t], s = v;
#pragma unroll
    for (int o = 1; o < 4; o <<= 1) {
      int u = __shfl_up(s, o);
      if (t >= o) s += u;
    }
    wsum[t] = s - v;
  }
  __syncthreads();
  int exc = wsum[wv] + inc - run;
  slabOff[t] = exc;
  if (t == 255) slabOff[256] = exc + run;   // = E
}

// ---- radix pass C: scatter (src,dst) into slab-contiguous part[] ----
__global__ __launch_bounds__(256) void scat_kernel(
    const unsigned int* __restrict__ eidx, const int* __restrict__ bcnt,
    const int* __restrict__ slabOff, uint2* __restrict__ part,
    int E, const int* __restrict__ flags)
{
  __shared__ int cur[256];
  int t = threadIdx.x;
  cur[t] = slabOff[t] + bcnt[blockIdx.x * 256 + t];
  __syncthreads();
  int e0 = blockIdx.x * PCH;
  const int i64 = flags[1];
  for (int i = t; i < PCH; i += 256) {
    int e = e0 + i; if (e >= E) break;
    int s, d;
    if (i64) { s = (int)eidx[2 * (size_t)e]; d = (int)eidx[2 * ((size_t)E + e)]; }
    else     { s = (int)eidx[e];             d = (int)eidx[(size_t)E + e]; }
    int pos = atomicAdd(&cur[d >> SHIFT], 1);
    part[pos] = make_uint2((unsigned)s, (unsigned)d);
  }
}

// ---- radix pass D: per-slab CSR build fully in LDS (deg, scan, fill) ----
__global__ __launch_bounds__(256) void slabcsr_kernel(
    const uint2* __restrict__ part, const int* __restrict__ slabOff,
    int* __restrict__ offs, int* __restrict__ srcP, int N, int nslab)
{
  __shared__ int deg[SLABN];
  __shared__ int wsum[4];
  int sl = blockIdx.x, t = threadIdx.x;
  int n0 = sl << SHIFT;
  int nn = N - n0; if (nn > SLABN) nn = SLABN;
  int s0 = slabOff[sl], s1 = slabOff[sl + 1];
  for (int i = t; i < SLABN; i += 256) deg[i] = 0;
  __syncthreads();
  for (int i = s0 + t; i < s1; i += 256)
    atomicAdd(&deg[(int)part[i].y - n0], 1);
  __syncthreads();
  // block-wide exclusive scan of deg[0..SLABN): 2 elems/thread
  int bi = t * 2;
  int l0 = deg[bi], l1 = deg[bi + 1];
  int s = l0 + l1;
  int ws = s;
#pragma unroll
  for (int o = 1; o < 64; o <<= 1) {
    int u = __shfl_up(ws, o);
    if ((t & 63) >= o) ws += u;
  }
  if ((t & 63) == 63) wsum[t >> 6] = ws;
  __syncthreads();
  if (t < 4) {
    int v = wsum[t], inc = v;
#pragma unroll
    for (int o = 1; o < 4; o <<= 1) {
      int u = __shfl_up(inc, o);
      if (t >= o) inc += u;
    }
    wsum[t] = inc - v;
  }
  __syncthreads();
  int run = wsum[t >> 6] + (ws - s);   // thread-exclusive base
  deg[bi] = run;
  if (bi < nn) offs[n0 + bi] = s0 + run;
  run += l0;
  deg[bi + 1] = run;
  if (bi + 1 < nn) offs[n0 + bi + 1] = s0 + run;
  __syncthreads();
  for (int i = s0 + t; i < s1; i += 256) {
    uint2 p = part[i];
    int pos = s0 + atomicAdd(&deg[(int)p.y - n0], 1);
    srcP[pos] = (int)p.x;
  }
  if (sl == nslab - 1 && t == 0) offs[N] = s1;
}

static inline __device__ float ldadapt(const void* p, size_t i, int isbf) {
  return isbf ? b2f(((const unsigned short*)p)[i]) : ((const float*)p)[i];
}

// ---- weight prep: W1b, W1tb, W2f, W2b64 ([256][64] bf16, zero-padded K), att ----
__global__ __launch_bounds__(256) void prep_weights(
    const void* __restrict__ W1, const void* __restrict__ W2,
    const void* __restrict__ aS, const void* __restrict__ aD,
    unsigned short* __restrict__ W1b, unsigned short* __restrict__ W1tb,
    float* __restrict__ W2f, unsigned short* __restrict__ W2b64,
    float* __restrict__ atS, float* __restrict__ atD,
    const int* __restrict__ flags)
{
  const int fb = flags[0];
  int i = blockIdx.x * 256 + threadIdx.x;
  if (i < INDIM * HIDD) {               // W1: [512][256]
    int r = i >> 8, c = i & 255;
    float w0 = ldadapt(W1, i, fb);
    unsigned short wb = f2b(w0);
    W1b[i] = wb;                        // Bt for h4: [512 rows][256 k]
    W1tb[c * INDIM + r] = wb;           // Bt for xp1: [256 rows][512 k]
  }
  if (i < HIDD * OUTD) {                // W2: [256][32]
    int r = i >> 5, c = i & 31;
    float w0 = ldadapt(W2, i, fb);
    W2f[i] = w0;
    W2b64[r * 64 + c] = f2b(w0);        // Bt for h3: [256 rows][64 k], upper 32 zero
    W2b64[r * 64 + 32 + c] = 0;
  }
  if (i < HIDD) { atS[i] = ldadapt(aS, i, fb); atD[i] = ldadapt(aD, i, fb); }
}

// =====================================================================
// m97-structure MFMA NT GEMM + T2 swizzle (rule #21 form: linear LDS dest
// for global_load_lds + inverse-swizzled GLOBAL source + swizzled ds_read).
// AMODE:   0 = A bf16 ws buffer; 1 = A external: fb ? bf16 : f32 reg-staged
// OUTMODE: 0 = bf16 to Cb; 1 = adaptive (flags[0]) to Out+outOff
// EPI:     0 = none; 1 = ELU before store
// =====================================================================
template<int AMODE, int OUTMODE, int EPI>
__global__ __launch_bounds__(256) void gemm_nt2(
    const void* __restrict__ Av, const unsigned short* __restrict__ Bt,
    unsigned short* __restrict__ Cb, void* __restrict__ Out, size_t outOff,
    const int* __restrict__ flags, int M, int Nn, int K)
{
  __shared__ unsigned short Als[128 * 64];
  __shared__ unsigned short Bls[128 * 64];
  const int tid = threadIdx.x, lane = tid & 63, wid = tid >> 6;
  const int wr = wid >> 1, wc = wid & 1;
  const int rowBase = blockIdx.y * 128, colBase = blockIdx.x * 128;
  const int fb = flags[0];

  const int srow = (lane >> 3), sg = lane & 7;
  const int sgx = sg ^ srow;           // inverse-swizzled source granule

  f32x4 acc[4][4] = {};

  for (int kt = 0; kt < K; kt += 64) {
    if (AMODE == 1 && !fb) {
      const float* Af = (const float*)Av;
#pragma unroll
      for (int i = 0; i < 4; ++i) {
        int row = wid * 32 + i * 8 + srow;
        int gr = rowBase + row; if (gr > M - 1) gr = M - 1;
        const float* sp = Af + (size_t)gr * K + kt + sg * 8;   // linear coalesced load
        float4 lo = *(const float4*)sp;
        float4 hi = *(const float4*)(sp + 4);
        union { unsigned short us[8]; int4 v; } cv;
        cv.us[0] = f2b(lo.x); cv.us[1] = f2b(lo.y); cv.us[2] = f2b(lo.z); cv.us[3] = f2b(lo.w);
        cv.us[4] = f2b(hi.x); cv.us[5] = f2b(hi.y); cv.us[6] = f2b(hi.z); cv.us[7] = f2b(hi.w);
        *(int4*)(Als + (wid * 4 + i) * 512 + srow * 64 + (sgx << 3)) = cv.v;
      }
    } else {
      const unsigned short* Ab = (const unsigned short*)Av;
#pragma unroll
      for (int i = 0; i < 4; ++i) {
        int row = wid * 32 + i * 8 + srow;
        int gr = rowBase + row;
        if (AMODE == 1 && gr > M - 1) gr = M - 1;   // external input: clamp
        gld16(Ab + (size_t)gr * K + kt + (sgx << 3), Als + (wid * 4 + i) * 512);
      }
    }
#pragma unroll
    for (int i = 0; i < 4; ++i) {
      int row = wid * 32 + i * 8 + srow;
      gld16(Bt + (size_t)(colBase + row) * K + kt + (sgx << 3), Bls + (wid * 4 + i) * 512);
    }
    __syncthreads();

    bf16x8 af[4], bfr[4];
#pragma unroll
    for (int ks = 0; ks < 2; ++ks) {
      int gl = ks * 4 + (lane >> 4);
      int gx = gl ^ (lane & 7);        // row&7 == lane&7 for fragment rows
#pragma unroll
      for (int mi = 0; mi < 4; ++mi) {
        int row = wr * 64 + mi * 16 + (lane & 15);
        af[mi] = *(const bf16x8*)(Als + row * 64 + (gx << 3));
      }
#pragma unroll
      for (int ni = 0; ni < 4; ++ni) {
        int row = wc * 64 + ni * 16 + (lane & 15);
        bfr[ni] = *(const bf16x8*)(Bls + row * 64 + (gx << 3));
      }
#pragma unroll
      for (int mi = 0; mi < 4; ++mi)
#pragma unroll
        for (int ni = 0; ni < 4; ++ni)
          acc[mi][ni] = __builtin_amdgcn_mfma_f32_16x16x32_bf16(af[mi], bfr[ni], acc[mi][ni], 0, 0, 0);
    }
    __syncthreads();
  }

  // C/D: col = lane&15, row = (lane>>4)*4 + reg
#pragma unroll
  for (int mi = 0; mi < 4; ++mi) {
    int r0 = rowBase + wr * 64 + mi * 16 + (lane >> 4) * 4;
#pragma unroll
    for (int ni = 0; ni < 4; ++ni) {
      int c = colBase + wc * 64 + ni * 16 + (lane & 15);
#pragma unroll
      for (int v = 0; v < 4; ++v) {
        int r = r0 + v;
        if (r < M) {
          size_t idx = (size_t)r * Nn + c;
          float x = acc[mi][ni][v];
          if (EPI) x = x > 0.f ? x : expm1f(x);
          if (OUTMODE == 0) Cb[idx] = f2b(x);
          else {
            if (fb) ((unsigned short*)Out)[outOff + idx] = f2b(x);
            else    ((float*)Out)[outOff + idx] = x;
          }
        }
      }
    }
  }
}

// ---- a_src / a_dst: one wave per node, dot(xp1_row, att); P is bf16 ----
__global__ __launch_bounds__(256) void rowdots(
    const unsigned short* __restrict__ P, const float* __restrict__ atS,
    const float* __restrict__ atD,
    float* __restrict__ asrc, float* __restrict__ adst, int N)
{
  int wave = threadIdx.x >> 6, lane = threadIdx.x & 63;
  int node = blockIdx.x * 4 + wave;
  if (node >= N) return;
  ushort4 u = *(const ushort4*)(P + (size_t)node * HIDD + lane * 4);
  float4 v = make_float4(b2f(u.x), b2f(u.y), b2f(u.z), b2f(u.w));
  float4 s = *(const float4*)(atS + lane * 4);
  float4 d = *(const float4*)(atD + lane * 4);
  float s1 = v.x * s.x + v.y * s.y + v.z * s.z + v.w * s.w;
  float s2 = v.x * d.x + v.y * d.y + v.z * d.z + v.w * d.w;
#pragma unroll
  for (int off = 32; off; off >>= 1) {
    s1 += __shfl_down(s1, off);
    s2 += __shfl_down(s2, off);
  }
  if (lane == 0) { asrc[node] = s1; adst[node] = s2; }
}

// ---- agg layer 1: wave/node, 16 gathers in flight, denominator in-loop ----
__global__ __launch_bounds__(256) void agg_elu2(
    const unsigned short* __restrict__ xp,
    const float* __restrict__ asrc, const float* __restrict__ adst,
    const int* __restrict__ srcP, const int* __restrict__ offs,
    unsigned short* __restrict__ hout, int N)
{
  __shared__ int   sS[4][64];
  __shared__ float sW[4][64];
  int wid = threadIdx.x >> 6, lane = threadIdx.x & 63;
  int node = blockIdx.x * 4 + wid;
  if (node >= N) return;
  const float ad = adst[node];
  int s0 = offs[node], s1 = offs[node + 1];
  float a0 = 0.f, a1 = 0.f, a2 = 0.f, a3 = 0.f, den = 0.f;
  for (int base = s0; base < s1; base += 64) {
    int cnt = s1 - base; if (cnt > 64) cnt = 64;
    if (lane < cnt) {
      int sv = srcP[base + lane];
      sS[wid][lane] = sv;
      sW[wid][lane] = edgew(asrc[sv] + ad);
    }
    asm volatile("s_waitcnt lgkmcnt(0)" ::: "memory");   // wave-local LDS RAW fence
    int j = 0;
    for (; j + 16 <= cnt; j += 16) {          // 16 gathers in flight
      ushort4 u[16];
#pragma unroll
      for (int q = 0; q < 16; ++q)
        u[q] = *(const ushort4*)(xp + (size_t)sS[wid][j + q] * HIDD + lane * 4);
#pragma unroll
      for (int q = 0; q < 16; ++q) {
        float wv = sW[wid][j + q];
        den += wv;
        a0 += wv * b2f(u[q].x); a1 += wv * b2f(u[q].y);
        a2 += wv * b2f(u[q].z); a3 += wv * b2f(u[q].w);
      }
    }
    for (; j + 8 <= cnt; j += 8) {
      ushort4 u[8];
#pragma unroll
      for (int q = 0; q < 8; ++q)
        u[q] = *(const ushort4*)(xp + (size_t)sS[wid][j + q] * HIDD + lane * 4);
#pragma unroll
      for (int q = 0; q < 8; ++q) {
        float wv = sW[wid][j + q];
        den += wv;
        a0 += wv * b2f(u[q].x); a1 += wv * b2f(u[q].y);
        a2 += wv * b2f(u[q].z); a3 += wv * b2f(u[q].w);
      }
    }
    for (; j < cnt; ++j) {
      int   sv = sS[wid][j];
      float wv = sW[wid][j];
      den += wv;
      ushort4 u = *(const ushort4*)(xp + (size_t)sv * HIDD + lane * 4);
      a0 += wv * b2f(u.x); a1 += wv * b2f(u.y); a2 += wv * b2f(u.z); a3 += wv * b2f(u.w);
    }
  }
  float inv = 1.f / (den + 1e-16f);
  float r0 = a0 * inv, r1 = a1 * inv, r2 = a2 * inv, r3 = a3 * inv;
  r0 = r0 > 0.f ? r0 : expm1f(r0);
  r1 = r1 > 0.f ? r1 : expm1f(r1);
  r2 = r2 > 0.f ? r2 : expm1f(r2);
  r3 = r3 > 0.f ? r3 : expm1f(r3);
  ushort4 o; o.x = f2b(r0); o.y = f2b(r1); o.z = f2b(r2); o.w = f2b(r3);
  *(ushort4*)(hout + (size_t)node * HIDD + lane * 4) = o;
}

// ---- h2 = h1 @ W2 ([N,256]x[256,32]) -> adaptive out + bf16 copy ----
__global__ __launch_bounds__(256) void gemm_h2(
    const unsigned short* __restrict__ H1, const float* __restrict__ W2f,
    void* __restrict__ Out, unsigned short* __restrict__ h2b,
    const int* __restrict__ flags, int M)
{
  const int fb = flags[0];
  __shared__ float Bs[HIDD][33];
  __shared__ float As[8][HIDD];
  int tid = threadIdx.x;
  int tx = tid & 31, ty = tid >> 5;
  int row0 = blockIdx.x * 8;
#pragma unroll
  for (int j = 0; j < 8; ++j) {            // W2 (256x32 f32) via float4
    int idx4 = tid + 256 * j;              // 2048 float4s
    float4 v = *(const float4*)(W2f + idx4 * 4);
    int k = idx4 >> 3, c = (idx4 & 7) * 4;
    Bs[k][c] = v.x; Bs[k][c + 1] = v.y; Bs[k][c + 2] = v.z; Bs[k][c + 3] = v.w;
  }
  {
    int flat = tid * 8;                    // 8 rows x 256 = 2048 bf16, 16B/thread
    int r = flat >> 8, k = flat & 255;
    int gr = row0 + r;
    if (gr < M) {
      ushort4 lo = *(const ushort4*)(H1 + (size_t)gr * HIDD + k);
      ushort4 hi = *(const ushort4*)(H1 + (size_t)gr * HIDD + k + 4);
      As[r][k] = b2f(lo.x); As[r][k + 1] = b2f(lo.y); As[r][k + 2] = b2f(lo.z); As[r][k + 3] = b2f(lo.w);
      As[r][k + 4] = b2f(hi.x); As[r][k + 5] = b2f(hi.y); As[r][k + 6] = b2f(hi.z); As[r][k + 7] = b2f(hi.w);
    } else {
#pragma unroll
      for (int q = 0; q < 8; ++q) As[r][k + q] = 0.f;
    }
  }
  __syncthreads();
  float acc = 0.f;
#pragma unroll 8
  for (int k = 0; k < HIDD; ++k) acc += As[ty][k] * Bs[k][tx];
  int row = row0 + ty;
  if (row < M) {
    size_t idx = (size_t)row * OUTD + tx;
    if (fb) ((unsigned short*)Out)[idx] = f2b(acc);
    else    ((float*)Out)[idx] = acc;
    h2b[idx] = f2b(acc);
  }
}

// ---- agg layer 2 on h2 [N,32] bf16 -> g2pad [N][64], w recomputed inline ----
__global__ __launch_bounds__(256) void agg_small(
    const unsigned short* __restrict__ h2b,
    const float* __restrict__ asrc, const float* __restrict__ adst,
    const int* __restrict__ srcP, const int* __restrict__ offs,
    unsigned short* __restrict__ g2pad, int N)
{
  int wid = threadIdx.x >> 6, lane = threadIdx.x & 63;
  int node = blockIdx.x * 4 + wid;
  if (node >= N) return;
  int grp = lane >> 4, cl = lane & 15;
  const float ad = adst[node];
  int s0 = offs[node], s1 = offs[node + 1];
  float a0 = 0.f, a1 = 0.f, den = 0.f;
  for (int e = s0 + grp; e < s1; e += 4) {
    int   sv = srcP[e];          // uniform across the 16-lane group (broadcast)
    float wv = edgew(asrc[sv] + ad);
    den += wv;
    ushort2 u = *(const ushort2*)(h2b + (size_t)sv * OUTD + cl * 2);
    a0 += wv * b2f(u.x);
    a1 += wv * b2f(u.y);
  }
  a0 += __shfl_xor(a0, 16); a0 += __shfl_xor(a0, 32);
  a1 += __shfl_xor(a1, 16); a1 += __shfl_xor(a1, 32);
  den += __shfl_xor(den, 16); den += __shfl_xor(den, 32);
  if (grp == 0) {
    float inv = 1.f / (den + 1e-16f);
    ushort2 o; o.x = f2b(a0 * inv); o.y = f2b(a1 * inv);
    *(ushort2*)(g2pad + (size_t)node * 64 + cl * 2) = o;
  } else if (grp == 1) {
    *(ushort2*)(g2pad + (size_t)node * 64 + 32 + cl * 2) = make_ushort2(0, 0);  // K-pad
  }
}

extern "C" void kernel_launch(void* const* d_in, const int* in_sizes, int n_in,
                              void* d_out, int out_size, void* d_ws, size_t ws_size,
                              hipStream_t stream)
{
  const void*         feat = d_in[0];
  const unsigned int* eidx = (const unsigned int*)d_in[1];
  const void*         W1   = d_in[2];
  const void*         W2   = d_in[3];
  const void*         aS   = d_in[4];
  const void*         aD   = d_in[5];

  const int N = in_sizes[0] / INDIM;
  const int E = in_sizes[1] / 2;
  const int M_pad = ((N + 127) / 128) * 128;
  const int nslab = (N + SLABN - 1) / SLABN;   // 196 for N=100000; must be <= 256
  const int npb = (E + PCH - 1) / PCH;

  char* w = (char*)d_ws;
  auto alloc = [&](size_t bytes) -> char* {
    char* p = w; w += (bytes + 255) & ~(size_t)255; return p;
  };
  unsigned short* H     = (unsigned short*)alloc((size_t)M_pad * HIDD * 2);  // h1 / h3
  unsigned short* P     = (unsigned short*)alloc((size_t)M_pad * HIDD * 2);  // xp1
  unsigned short* h2b   = (unsigned short*)alloc((size_t)N * OUTD * 2);      // h2 bf16
  unsigned short* g2pad = (unsigned short*)alloc((size_t)M_pad * 64 * 2);    // agg(h2), K-padded
  float* asrc = (float*)alloc((size_t)N * 4);
  float* adst = (float*)alloc((size_t)N * 4);
  int*   srcP = (int*)alloc((size_t)E * 4);     // CSR-ordered edge src
  uint2* part = (uint2*)alloc((size_t)E * 8);   // slab-partitioned (src,dst)
  int*   offs = (int*)alloc((size_t)(N + 1) * 4);
  int*   bcnt = (int*)alloc((size_t)npb * 256 * 4);
  int*   slabOff = (int*)alloc(257 * 4);
  unsigned short* W1b   = (unsigned short*)alloc((size_t)INDIM * HIDD * 2); // [512][256]
  unsigned short* W1tb  = (unsigned short*)alloc((size_t)INDIM * HIDD * 2); // [256][512]
  unsigned short* W2b64 = (unsigned short*)alloc((size_t)HIDD * 64 * 2);    // [256][64]
  float* W2f  = (float*)alloc((size_t)HIDD * OUTD * 4);
  float* atS  = (float*)alloc((size_t)HIDD * 4);
  float* atD  = (float*)alloc((size_t)HIDD * 4);
  int*   flags = (int*)alloc(64);

  probe_kernel<<<1, 256, 0, stream>>>((const unsigned int*)feat, eidx, flags);

  // CSR build: radix by dst-slab (512-node slabs), slab-local CSR in LDS
  cnt_kernel<<<npb, 256, 0, stream>>>(eidx, bcnt, E, flags);
  bscan_kernel<<<1, 256, 0, stream>>>(bcnt, slabOff, npb);
  scat_kernel<<<npb, 256, 0, stream>>>(eidx, bcnt, slabOff, part, E, flags);
  slabcsr_kernel<<<nslab, 256, 0, stream>>>(part, slabOff, offs, srcP, N, nslab);

  prep_weights<<<512, 256, 0, stream>>>(W1, W2, aS, aD, W1b, W1tb, W2f, W2b64, atS, atD, flags);

  const int mb = (N + 127) / 128;

  // xp1 = feat @ W1 (f32 A converted in staging, or bf16 gld16 per flag)
  gemm_nt2<1, 0, 0><<<dim3(HIDD / 128, mb), 256, 0, stream>>>(
      feat, W1tb, P, nullptr, 0, flags, N, HIDD, INDIM);

  rowdots<<<(N + 3) / 4, 256, 0, stream>>>(P, atS, atD, asrc, adst, N);

  // GAT layer 1: h1 = elu(agg(xp1)/denom)
  agg_elu2<<<(N + 3) / 4, 256, 0, stream>>>(P, asrc, adst, srcP, offs, H, N);

  // h2 = h1 @ W2 -> output 0 (+ bf16 copy for layer-2 agg)
  gemm_h2<<<(N + 7) / 8, 256, 0, stream>>>(H, W2f, d_out, h2b, flags, N);

  // GAT layer 2, commuted: g2 = agg(h2) [N,32->64pad]
  agg_small<<<(N + 3) / 4, 256, 0, stream>>>(h2b, asrc, adst, srcP, offs, g2pad, N);

  // h3 = elu(g2 @ W2^T) via MFMA GEMM
  gemm_nt2<0, 0, 1><<<dim3(HIDD / 128, mb), 256, 0, stream>>>(
      g2pad, W2b64, H, nullptr, 0, flags, N, HIDD, 64);

  // h4 = h3 @ W1^T -> output 1 (adaptive)
  gemm_nt2<0, 1, 0><<<dim3(INDIM / 128, mb), 256, 0, stream>>>(
      H, W1b, nullptr, d_out, (size_t)N * OUTD, flags, N, INDIM, HIDD);
}

// Round 14
// 651.932 us; speedup vs baseline: 1.2549x; 1.0091x over previous
//
#include <hip/hip_runtime.h>
#include <cstdint>
#include <cstddef>

#define INDIM 512
#define HIDD  256
#define OUTD  32
#define PCH   4096      // edges per radix block
#define SHIFT 9
#define SLABN 512       // nodes per slab; nslab <= 256

typedef __attribute__((ext_vector_type(4))) float f32x4;
typedef __attribute__((ext_vector_type(8))) short bf16x8;

// ---- bf16 <-> f32 helpers ----
static inline __device__ float b2f(unsigned short u) {
  union { float f; unsigned int i; } v; v.i = ((unsigned int)u) << 16; return v.f;
}
static inline __device__ unsigned short f2b(float f) {
  union { float f; unsigned int i; } v; v.f = f;
  unsigned int x = v.i;
  x += 0x7fffu + ((x >> 16) & 1u);   // round-to-nearest-even
  return (unsigned short)(x >> 16);
}

// edge weight: exp(sigmoid(x)) — SAME formula in both agg kernels
static inline __device__ float edgew(float x) {
  float al = 1.f / (1.f + __expf(-x));
  return __expf(al);
}

// async global->LDS, 16B per lane. LDS dest = wave-uniform base + lane*16.
static __device__ __forceinline__ void gld16(const unsigned short* g, unsigned short* l) {
  __builtin_amdgcn_global_load_lds(
      (const __attribute__((address_space(1))) void*)g,
      (__attribute__((address_space(3))) void*)l, 16, 0, 0);
}

// ---- runtime dtype probe ----
__global__ __launch_bounds__(256) void probe_kernel(
    const unsigned int* __restrict__ feat, const unsigned int* __restrict__ eidx,
    int* __restrict__ flags)
{
  int t = threadIdx.x;
  __shared__ int cnt, oddnz;
  if (t == 0) { cnt = 0; oddnz = 0; }
  __syncthreads();
  unsigned int w = feat[t];
  unsigned short lo = (unsigned short)(w & 0xFFFFu);
  int e = (lo >> 7) & 0xFF;
  int plausible = ((lo & 0x7FFF) == 0) || (e >= 0x60 && e <= 0x9F);
  atomicAdd(&cnt, plausible);
  if (t & 1) { if (eidx[t] != 0u) atomicAdd(&oddnz, 1); }
  __syncthreads();
  if (t == 0) { flags[0] = (cnt >= 192) ? 1 : 0; flags[1] = (oddnz == 0) ? 1 : 0; }
}

// ---- radix pass A: per-block slab counts (LDS hist, plain global writes) ----
__global__ __launch_bounds__(256) void cnt_kernel(
    const unsigned int* __restrict__ eidx, int* __restrict__ bcnt,
    int E, const int* __restrict__ flags)
{
  __shared__ int hist[256];
  int t = threadIdx.x;
  hist[t] = 0;
  __syncthreads();
  int e0 = blockIdx.x * PCH;
  const int i64 = flags[1];
  for (int i = t; i < PCH; i += 256) {
    int e = e0 + i; if (e >= E) break;
    int d = i64 ? (int)eidx[2 * ((size_t)E + e)] : (int)eidx[(size_t)E + e];
    atomicAdd(&hist[d >> SHIFT], 1);
  }
  __syncthreads();
  bcnt[blockIdx.x * 256 + t] = hist[t];
}

// ---- radix pass B: bcnt -> within-slab block prefixes; slabOff excl scan ----
__global__ __launch_bounds__(256) void bscan_kernel(
    int* __restrict__ bcnt, int* __restrict__ slabOff, int npb)
{
  __shared__ int wsum[4];
  int t = threadIdx.x, lane = t & 63, wv = t >> 6;
  int run = 0;
  for (int b = 0; b < npb; ++b) {
    int v = bcnt[b * 256 + t];
    bcnt[b * 256 + t] = run;     // within-slab prefix
    run += v;
  }
  int inc = run;
#pragma unroll
  for (int o = 1; o < 64; o <<= 1) {
    int u = __shfl_up(inc, o);
    if (lane >= o) inc += u;
  }
  if (lane == 63) wsum[wv] = inc;
  __syncthreads();
  if (t < 4) {
    int v = wsum[t], s = v;
#pragma unroll
    for (int o = 1; o < 4; o <<= 1) {
      int u = __shfl_up(s, o);
      if (t >= o) s += u;
    }
    wsum[t] = s - v;
  }
  __syncthreads();
  int exc = wsum[wv] + inc - run;
  slabOff[t] = exc;
  if (t == 255) slabOff[256] = exc + run;   // = E
}

// ---- radix pass C: scatter (src,dst) into slab-contiguous part[] ----
__global__ __launch_bounds__(256) void scat_kernel(
    const unsigned int* __restrict__ eidx, const int* __restrict__ bcnt,
    const int* __restrict__ slabOff, uint2* __restrict__ part,
    int E, const int* __restrict__ flags)
{
  __shared__ int cur[256];
  int t = threadIdx.x;
  cur[t] = slabOff[t] + bcnt[blockIdx.x * 256 + t];
  __syncthreads();
  int e0 = blockIdx.x * PCH;
  const int i64 = flags[1];
  for (int i = t; i < PCH; i += 256) {
    int e = e0 + i; if (e >= E) break;
    int s, d;
    if (i64) { s = (int)eidx[2 * (size_t)e]; d = (int)eidx[2 * ((size_t)E + e)]; }
    else     { s = (int)eidx[e];             d = (int)eidx[(size_t)E + e]; }
    int pos = atomicAdd(&cur[d >> SHIFT], 1);
    part[pos] = make_uint2((unsigned)s, (unsigned)d);
  }
}

// ---- radix pass D: per-slab CSR build fully in LDS (deg, scan, fill) ----
__global__ __launch_bounds__(256) void slabcsr_kernel(
    const uint2* __restrict__ part, const int* __restrict__ slabOff,
    int* __restrict__ offs, int* __restrict__ srcP, int N, int nslab)
{
  __shared__ int deg[SLABN];
  __shared__ int wsum[4];
  int sl = blockIdx.x, t = threadIdx.x;
  int n0 = sl << SHIFT;
  int nn = N - n0; if (nn > SLABN) nn = SLABN;
  int s0 = slabOff[sl], s1 = slabOff[sl + 1];
  for (int i = t; i < SLABN; i += 256) deg[i] = 0;
  __syncthreads();
  for (int i = s0 + t; i < s1; i += 256)
    atomicAdd(&deg[(int)part[i].y - n0], 1);
  __syncthreads();
  int bi = t * 2;
  int l0 = deg[bi], l1 = deg[bi + 1];
  int s = l0 + l1;
  int ws = s;
#pragma unroll
  for (int o = 1; o < 64; o <<= 1) {
    int u = __shfl_up(ws, o);
    if ((t & 63) >= o) ws += u;
  }
  if ((t & 63) == 63) wsum[t >> 6] = ws;
  __syncthreads();
  if (t < 4) {
    int v = wsum[t], inc = v;
#pragma unroll
    for (int o = 1; o < 4; o <<= 1) {
      int u = __shfl_up(inc, o);
      if (t >= o) inc += u;
    }
    wsum[t] = inc - v;
  }
  __syncthreads();
  int run = wsum[t >> 6] + (ws - s);   // thread-exclusive base
  deg[bi] = run;
  if (bi < nn) offs[n0 + bi] = s0 + run;
  run += l0;
  deg[bi + 1] = run;
  if (bi + 1 < nn) offs[n0 + bi + 1] = s0 + run;
  __syncthreads();
  for (int i = s0 + t; i < s1; i += 256) {
    uint2 p = part[i];
    int pos = s0 + atomicAdd(&deg[(int)p.y - n0], 1);
    srcP[pos] = (int)p.x;
  }
  if (sl == nslab - 1 && t == 0) offs[N] = s1;
}

static inline __device__ float ldadapt(const void* p, size_t i, int isbf) {
  return isbf ? b2f(((const unsigned short*)p)[i]) : ((const float*)p)[i];
}

// ---- weight prep: W1b, W1tb, W2f, W2b64 ([256][64] bf16, zero-padded K), att ----
__global__ __launch_bounds__(256) void prep_weights(
    const void* __restrict__ W1, const void* __restrict__ W2,
    const void* __restrict__ aS, const void* __restrict__ aD,
    unsigned short* __restrict__ W1b, unsigned short* __restrict__ W1tb,
    float* __restrict__ W2f, unsigned short* __restrict__ W2b64,
    float* __restrict__ atS, float* __restrict__ atD,
    const int* __restrict__ flags)
{
  const int fb = flags[0];
  int i = blockIdx.x * 256 + threadIdx.x;
  if (i < INDIM * HIDD) {               // W1: [512][256]
    int r = i >> 8, c = i & 255;
    float w0 = ldadapt(W1, i, fb);
    unsigned short wb = f2b(w0);
    W1b[i] = wb;                        // Bt for h4: [512 rows][256 k]
    W1tb[c * INDIM + r] = wb;           // Bt for xp1: [256 rows][512 k]
  }
  if (i < HIDD * OUTD) {                // W2: [256][32]
    int r = i >> 5, c = i & 31;
    float w0 = ldadapt(W2, i, fb);
    W2f[i] = w0;
    W2b64[r * 64 + c] = f2b(w0);        // Bt for h3: [256 rows][64 k], upper 32 zero
    W2b64[r * 64 + 32 + c] = 0;
  }
  if (i < HIDD) { atS[i] = ldadapt(aS, i, fb); atD[i] = ldadapt(aD, i, fb); }
}

// =====================================================================
// MFMA NT GEMM, T2-swizzled + 2-phase double-buffered K-loop (T3 recipe):
// stage tile t+1 into buf^1 BEFORE computing tile t, one barrier/K-step —
// the compiler's pre-barrier vmcnt(0) drain lands AFTER the MFMA work.
// f32-A path uses T14 split: global loads issued early, convert+ds_write
// after compute (vmcnt wait lands post-MFMA).
// AMODE:   0 = A bf16 ws buffer; 1 = A external: fb ? bf16 : f32 reg-staged
// OUTMODE: 0 = bf16 to Cb; 1 = adaptive (flags[0]) to Out+outOff
// EPI:     0 = none; 1 = ELU before store
// =====================================================================
template<int AMODE, int OUTMODE, int EPI>
__global__ __launch_bounds__(256) void gemm_nt2(
    const void* __restrict__ Av, const unsigned short* __restrict__ Bt,
    unsigned short* __restrict__ Cb, void* __restrict__ Out, size_t outOff,
    const int* __restrict__ flags, int M, int Nn, int K)
{
  __shared__ unsigned short Als[2][128 * 64];   // 2 x 16KB
  __shared__ unsigned short Bls[2][128 * 64];
  const int tid = threadIdx.x, lane = tid & 63, wid = tid >> 6;
  const int wr = wid >> 1, wc = wid & 1;
  const int rowBase = blockIdx.y * 128, colBase = blockIdx.x * 128;
  const int fb = flags[0];

  const int srow = (lane >> 3), sg = lane & 7;
  const int sgx = sg ^ srow;           // inverse-swizzled source granule

  f32x4 acc[4][4] = {};
  const int nt = K / 64;

  auto stageB16 = [&](int buf, int kt) {
#pragma unroll
    for (int i = 0; i < 4; ++i) {
      int row = wid * 32 + i * 8 + srow;
      gld16(Bt + (size_t)(colBase + row) * K + kt + (sgx << 3), &Bls[buf][(wid * 4 + i) * 512]);
    }
  };
  auto stageA16 = [&](int buf, int kt) {
    const unsigned short* Ab = (const unsigned short*)Av;
#pragma unroll
    for (int i = 0; i < 4; ++i) {
      int row = wid * 32 + i * 8 + srow;
      int gr = rowBase + row;
      if (AMODE == 1 && gr > M - 1) gr = M - 1;   // external input: clamp
      gld16(Ab + (size_t)gr * K + kt + (sgx << 3), &Als[buf][(wid * 4 + i) * 512]);
    }
  };
  float4 pf[8];                        // f32-A prefetch regs (lo,hi x 4 instr)
  auto loadAf32 = [&](int kt) {
    const float* Af = (const float*)Av;
#pragma unroll
    for (int i = 0; i < 4; ++i) {
      int row = wid * 32 + i * 8 + srow;
      int gr = rowBase + row; if (gr > M - 1) gr = M - 1;
      const float* sp = Af + (size_t)gr * K + kt + sg * 8;   // linear coalesced
      pf[2 * i] = *(const float4*)sp;
      pf[2 * i + 1] = *(const float4*)(sp + 4);
    }
  };
  auto writeAf32 = [&](int buf) {
#pragma unroll
    for (int i = 0; i < 4; ++i) {
      float4 lo = pf[2 * i], hi = pf[2 * i + 1];
      union { unsigned short us[8]; int4 v; } cv;
      cv.us[0] = f2b(lo.x); cv.us[1] = f2b(lo.y); cv.us[2] = f2b(lo.z); cv.us[3] = f2b(lo.w);
      cv.us[4] = f2b(hi.x); cv.us[5] = f2b(hi.y); cv.us[6] = f2b(hi.z); cv.us[7] = f2b(hi.w);
      // swizzled ds_write: data of granule sg lands at physical slot sgx
      *(int4*)(&Als[buf][(wid * 4 + i) * 512 + srow * 64 + (sgx << 3)]) = cv.v;
    }
  };
  auto compute = [&](int buf) {
    bf16x8 af[4], bfr[4];
#pragma unroll
    for (int ks = 0; ks < 2; ++ks) {
      int gl = ks * 4 + (lane >> 4);
      int gx = gl ^ (lane & 7);        // row&7 == lane&7 for fragment rows
#pragma unroll
      for (int mi = 0; mi < 4; ++mi) {
        int row = wr * 64 + mi * 16 + (lane & 15);
        af[mi] = *(const bf16x8*)(&Als[buf][row * 64 + (gx << 3)]);
      }
#pragma unroll
      for (int ni = 0; ni < 4; ++ni) {
        int row = wc * 64 + ni * 16 + (lane & 15);
        bfr[ni] = *(const bf16x8*)(&Bls[buf][row * 64 + (gx << 3)]);
      }
#pragma unroll
      for (int mi = 0; mi < 4; ++mi)
#pragma unroll
        for (int ni = 0; ni < 4; ++ni)
          acc[mi][ni] = __builtin_amdgcn_mfma_f32_16x16x32_bf16(af[mi], bfr[ni], acc[mi][ni], 0, 0, 0);
    }
  };

  if (AMODE == 1 && !fb) {
    loadAf32(0);
    writeAf32(0);
    stageB16(0, 0);
    __syncthreads();
    int cur = 0;
    for (int t = 0; t < nt; ++t) {
      if (t + 1 < nt) { loadAf32((t + 1) * 64); stageB16(cur ^ 1, (t + 1) * 64); }
      compute(cur);
      if (t + 1 < nt) writeAf32(cur ^ 1);   // vmcnt wait lands here, post-MFMA
      __syncthreads();
      cur ^= 1;
    }
  } else {
    stageA16(0, 0); stageB16(0, 0);
    __syncthreads();
    int cur = 0;
    for (int t = 0; t < nt; ++t) {
      if (t + 1 < nt) { stageA16(cur ^ 1, (t + 1) * 64); stageB16(cur ^ 1, (t + 1) * 64); }
      compute(cur);
      __syncthreads();                      // drains next-tile vmcnt post-MFMA
      cur ^= 1;
    }
  }

  // C/D: col = lane&15, row = (lane>>4)*4 + reg
#pragma unroll
  for (int mi = 0; mi < 4; ++mi) {
    int r0 = rowBase + wr * 64 + mi * 16 + (lane >> 4) * 4;
#pragma unroll
    for (int ni = 0; ni < 4; ++ni) {
      int c = colBase + wc * 64 + ni * 16 + (lane & 15);
#pragma unroll
      for (int v = 0; v < 4; ++v) {
        int r = r0 + v;
        if (r < M) {
          size_t idx = (size_t)r * Nn + c;
          float x = acc[mi][ni][v];
          if (EPI) x = x > 0.f ? x : expm1f(x);
          if (OUTMODE == 0) Cb[idx] = f2b(x);
          else {
            if (fb) ((unsigned short*)Out)[outOff + idx] = f2b(x);
            else    ((float*)Out)[outOff + idx] = x;
          }
        }
      }
    }
  }
}

// ---- a_src / a_dst: one wave per node, dot(xp1_row, att); P is bf16 ----
__global__ __launch_bounds__(256) void rowdots(
    const unsigned short* __restrict__ P, const float* __restrict__ atS,
    const float* __restrict__ atD,
    float* __restrict__ asrc, float* __restrict__ adst, int N)
{
  int wave = threadIdx.x >> 6, lane = threadIdx.x & 63;
  int node = blockIdx.x * 4 + wave;
  if (node >= N) return;
  ushort4 u = *(const ushort4*)(P + (size_t)node * HIDD + lane * 4);
  float4 v = make_float4(b2f(u.x), b2f(u.y), b2f(u.z), b2f(u.w));
  float4 s = *(const float4*)(atS + lane * 4);
  float4 d = *(const float4*)(atD + lane * 4);
  float s1 = v.x * s.x + v.y * s.y + v.z * s.z + v.w * s.w;
  float s2 = v.x * d.x + v.y * d.y + v.z * d.z + v.w * d.w;
#pragma unroll
  for (int off = 32; off; off >>= 1) {
    s1 += __shfl_down(s1, off);
    s2 += __shfl_down(s2, off);
  }
  if (lane == 0) { asrc[node] = s1; adst[node] = s2; }
}

// ---- agg layer 1: wave/node, 16 gathers in flight, denominator in-loop ----
__global__ __launch_bounds__(256) void agg_elu2(
    const unsigned short* __restrict__ xp,
    const float* __restrict__ asrc, const float* __restrict__ adst,
    const int* __restrict__ srcP, const int* __restrict__ offs,
    unsigned short* __restrict__ hout, int N)
{
  __shared__ int   sS[4][64];
  __shared__ float sW[4][64];
  int wid = threadIdx.x >> 6, lane = threadIdx.x & 63;
  int node = blockIdx.x * 4 + wid;
  if (node >= N) return;
  const float ad = adst[node];
  int s0 = offs[node], s1 = offs[node + 1];
  float a0 = 0.f, a1 = 0.f, a2 = 0.f, a3 = 0.f, den = 0.f;
  for (int base = s0; base < s1; base += 64) {
    int cnt = s1 - base; if (cnt > 64) cnt = 64;
    if (lane < cnt) {
      int sv = srcP[base + lane];
      sS[wid][lane] = sv;
      sW[wid][lane] = edgew(asrc[sv] + ad);
    }
    asm volatile("s_waitcnt lgkmcnt(0)" ::: "memory");   // wave-local LDS RAW fence
    int j = 0;
    for (; j + 16 <= cnt; j += 16) {          // 16 gathers in flight
      ushort4 u[16];
#pragma unroll
      for (int q = 0; q < 16; ++q)
        u[q] = *(const ushort4*)(xp + (size_t)sS[wid][j + q] * HIDD + lane * 4);
#pragma unroll
      for (int q = 0; q < 16; ++q) {
        float wv = sW[wid][j + q];
        den += wv;
        a0 += wv * b2f(u[q].x); a1 += wv * b2f(u[q].y);
        a2 += wv * b2f(u[q].z); a3 += wv * b2f(u[q].w);
      }
    }
    for (; j + 8 <= cnt; j += 8) {
      ushort4 u[8];
#pragma unroll
      for (int q = 0; q < 8; ++q)
        u[q] = *(const ushort4*)(xp + (size_t)sS[wid][j + q] * HIDD + lane * 4);
#pragma unroll
      for (int q = 0; q < 8; ++q) {
        float wv = sW[wid][j + q];
        den += wv;
        a0 += wv * b2f(u[q].x); a1 += wv * b2f(u[q].y);
        a2 += wv * b2f(u[q].z); a3 += wv * b2f(u[q].w);
      }
    }
    for (; j < cnt; ++j) {
      int   sv = sS[wid][j];
      float wv = sW[wid][j];
      den += wv;
      ushort4 u = *(const ushort4*)(xp + (size_t)sv * HIDD + lane * 4);
      a0 += wv * b2f(u.x); a1 += wv * b2f(u.y); a2 += wv * b2f(u.z); a3 += wv * b2f(u.w);
    }
  }
  float inv = 1.f / (den + 1e-16f);
  float r0 = a0 * inv, r1 = a1 * inv, r2 = a2 * inv, r3 = a3 * inv;
  r0 = r0 > 0.f ? r0 : expm1f(r0);
  r1 = r1 > 0.f ? r1 : expm1f(r1);
  r2 = r2 > 0.f ? r2 : expm1f(r2);
  r3 = r3 > 0.f ? r3 : expm1f(r3);
  ushort4 o; o.x = f2b(r0); o.y = f2b(r1); o.z = f2b(r2); o.w = f2b(r3);
  *(ushort4*)(hout + (size_t)node * HIDD + lane * 4) = o;
}

// ---- h2 = h1 @ W2 ([N,256]x[256,32]) -> adaptive out + bf16 copy ----
__global__ __launch_bounds__(256) void gemm_h2(
    const unsigned short* __restrict__ H1, const float* __restrict__ W2f,
    void* __restrict__ Out, unsigned short* __restrict__ h2b,
    const int* __restrict__ flags, int M)
{
  const int fb = flags[0];
  __shared__ float Bs[HIDD][33];
  __shared__ float As[8][HIDD];
  int tid = threadIdx.x;
  int tx = tid & 31, ty = tid >> 5;
  int row0 = blockIdx.x * 8;
#pragma unroll
  for (int j = 0; j < 8; ++j) {            // W2 (256x32 f32) via float4
    int idx4 = tid + 256 * j;              // 2048 float4s
    float4 v = *(const float4*)(W2f + idx4 * 4);
    int k = idx4 >> 3, c = (idx4 & 7) * 4;
    Bs[k][c] = v.x; Bs[k][c + 1] = v.y; Bs[k][c + 2] = v.z; Bs[k][c + 3] = v.w;
  }
  {
    int flat = tid * 8;                    // 8 rows x 256 = 2048 bf16, 16B/thread
    int r = flat >> 8, k = flat & 255;
    int gr = row0 + r;
    if (gr < M) {
      ushort4 lo = *(const ushort4*)(H1 + (size_t)gr * HIDD + k);
      ushort4 hi = *(const ushort4*)(H1 + (size_t)gr * HIDD + k + 4);
      As[r][k] = b2f(lo.x); As[r][k + 1] = b2f(lo.y); As[r][k + 2] = b2f(lo.z); As[r][k + 3] = b2f(lo.w);
      As[r][k + 4] = b2f(hi.x); As[r][k + 5] = b2f(hi.y); As[r][k + 6] = b2f(hi.z); As[r][k + 7] = b2f(hi.w);
    } else {
#pragma unroll
      for (int q = 0; q < 8; ++q) As[r][k + q] = 0.f;
    }
  }
  __syncthreads();
  float acc = 0.f;
#pragma unroll 8
  for (int k = 0; k < HIDD; ++k) acc += As[ty][k] * Bs[k][tx];
  int row = row0 + ty;
  if (row < M) {
    size_t idx = (size_t)row * OUTD + tx;
    if (fb) ((unsigned short*)Out)[idx] = f2b(acc);
    else    ((float*)Out)[idx] = acc;
    h2b[idx] = f2b(acc);
  }
}

// ---- agg layer 2 on h2 [N,32] bf16 -> g2pad [N][64], w recomputed inline ----
__global__ __launch_bounds__(256) void agg_small(
    const unsigned short* __restrict__ h2b,
    const float* __restrict__ asrc, const float* __restrict__ adst,
    const int* __restrict__ srcP, const int* __restrict__ offs,
    unsigned short* __restrict__ g2pad, int N)
{
  int wid = threadIdx.x >> 6, lane = threadIdx.x & 63;
  int node = blockIdx.x * 4 + wid;
  if (node >= N) return;
  int grp = lane >> 4, cl = lane & 15;
  const float ad = adst[node];
  int s0 = offs[node], s1 = offs[node + 1];
  float a0 = 0.f, a1 = 0.f, den = 0.f;
  for (int e = s0 + grp; e < s1; e += 4) {
    int   sv = srcP[e];          // uniform across the 16-lane group (broadcast)
    float wv = edgew(asrc[sv] + ad);
    den += wv;
    ushort2 u = *(const ushort2*)(h2b + (size_t)sv * OUTD + cl * 2);
    a0 += wv * b2f(u.x);
    a1 += wv * b2f(u.y);
  }
  a0 += __shfl_xor(a0, 16); a0 += __shfl_xor(a0, 32);
  a1 += __shfl_xor(a1, 16); a1 += __shfl_xor(a1, 32);
  den += __shfl_xor(den, 16); den += __shfl_xor(den, 32);
  if (grp == 0) {
    float inv = 1.f / (den + 1e-16f);
    ushort2 o; o.x = f2b(a0 * inv); o.y = f2b(a1 * inv);
    *(ushort2*)(g2pad + (size_t)node * 64 + cl * 2) = o;
  } else if (grp == 1) {
    *(ushort2*)(g2pad + (size_t)node * 64 + 32 + cl * 2) = make_ushort2(0, 0);  // K-pad
  }
}

extern "C" void kernel_launch(void* const* d_in, const int* in_sizes, int n_in,
                              void* d_out, int out_size, void* d_ws, size_t ws_size,
                              hipStream_t stream)
{
  const void*         feat = d_in[0];
  const unsigned int* eidx = (const unsigned int*)d_in[1];
  const void*         W1   = d_in[2];
  const void*         W2   = d_in[3];
  const void*         aS   = d_in[4];
  const void*         aD   = d_in[5];

  const int N = in_sizes[0] / INDIM;
  const int E = in_sizes[1] / 2;
  const int M_pad = ((N + 127) / 128) * 128;
  const int nslab = (N + SLABN - 1) / SLABN;   // 196 for N=100000; must be <= 256
  const int npb = (E + PCH - 1) / PCH;

  char* w = (char*)d_ws;
  auto alloc = [&](size_t bytes) -> char* {
    char* p = w; w += (bytes + 255) & ~(size_t)255; return p;
  };
  unsigned short* H     = (unsigned short*)alloc((size_t)M_pad * HIDD * 2);  // h1 / h3
  unsigned short* P     = (unsigned short*)alloc((size_t)M_pad * HIDD * 2);  // xp1
  unsigned short* h2b   = (unsigned short*)alloc((size_t)N * OUTD * 2);      // h2 bf16
  unsigned short* g2pad = (unsigned short*)alloc((size_t)M_pad * 64 * 2);    // agg(h2), K-padded
  float* asrc = (float*)alloc((size_t)N * 4);
  float* adst = (float*)alloc((size_t)N * 4);
  int*   srcP = (int*)alloc((size_t)E * 4);     // CSR-ordered edge src
  uint2* part = (uint2*)alloc((size_t)E * 8);   // slab-partitioned (src,dst)
  int*   offs = (int*)alloc((size_t)(N + 1) * 4);
  int*   bcnt = (int*)alloc((size_t)npb * 256 * 4);
  int*   slabOff = (int*)alloc(257 * 4);
  unsigned short* W1b   = (unsigned short*)alloc((size_t)INDIM * HIDD * 2); // [512][256]
  unsigned short* W1tb  = (unsigned short*)alloc((size_t)INDIM * HIDD * 2); // [256][512]
  unsigned short* W2b64 = (unsigned short*)alloc((size_t)HIDD * 64 * 2);    // [256][64]
  float* W2f  = (float*)alloc((size_t)HIDD * OUTD * 4);
  float* atS  = (float*)alloc((size_t)HIDD * 4);
  float* atD  = (float*)alloc((size_t)HIDD * 4);
  int*   flags = (int*)alloc(64);

  probe_kernel<<<1, 256, 0, stream>>>((const unsigned int*)feat, eidx, flags);

  // CSR build: radix by dst-slab (512-node slabs), slab-local CSR in LDS
  cnt_kernel<<<npb, 256, 0, stream>>>(eidx, bcnt, E, flags);
  bscan_kernel<<<1, 256, 0, stream>>>(bcnt, slabOff, npb);
  scat_kernel<<<npb, 256, 0, stream>>>(eidx, bcnt, slabOff, part, E, flags);
  slabcsr_kernel<<<nslab, 256, 0, stream>>>(part, slabOff, offs, srcP, N, nslab);

  prep_weights<<<512, 256, 0, stream>>>(W1, W2, aS, aD, W1b, W1tb, W2f, W2b64, atS, atD, flags);

  const int mb = (N + 127) / 128;

  // xp1 = feat @ W1 (f32 A converted in staging, or bf16 gld16 per flag)
  gemm_nt2<1, 0, 0><<<dim3(HIDD / 128, mb), 256, 0, stream>>>(
      feat, W1tb, P, nullptr, 0, flags, N, HIDD, INDIM);

  rowdots<<<(N + 3) / 4, 256, 0, stream>>>(P, atS, atD, asrc, adst, N);

  // GAT layer 1: h1 = elu(agg(xp1)/denom)
  agg_elu2<<<(N + 3) / 4, 256, 0, stream>>>(P, asrc, adst, srcP, offs, H, N);

  // h2 = h1 @ W2 -> output 0 (+ bf16 copy for layer-2 agg)
  gemm_h2<<<(N + 7) / 8, 256, 0, stream>>>(H, W2f, d_out, h2b, flags, N);

  // GAT layer 2, commuted: g2 = agg(h2) [N,32->64pad]
  agg_small<<<(N + 3) / 4, 256, 0, stream>>>(h2b, asrc, adst, srcP, offs, g2pad, N);

  // h3 = elu(g2 @ W2^T) via MFMA GEMM
  gemm_nt2<0, 0, 1><<<dim3(HIDD / 128, mb), 256, 0, stream>>>(
      g2pad, W2b64, H, nullptr, 0, flags, N, HIDD, 64);

  // h4 = h3 @ W1^T -> output 1 (adaptive)
  gemm_nt2<0, 1, 0><<<dim3(INDIM / 128, mb), 256, 0, stream>>>(
      H, W1b, nullptr, d_out, (size_t)N * OUTD, flags, N, INDIM, HIDD);
}

// Round 15
// 609.602 us; speedup vs baseline: 1.3420x; 1.0694x over previous
//
#include <hip/hip_runtime.h>
#include <cstdint>
#include <cstddef>

#define INDIM 512
#define HIDD  256
#define OUTD  32
#define PCH   4096      // edges per radix block
#define SHIFT 9
#define SLABN 512       // nodes per slab; nslab <= 256

typedef __attribute__((ext_vector_type(4))) float f32x4;
typedef __attribute__((ext_vector_type(8))) short bf16x8;

// ---- bf16 <-> f32 helpers ----
static inline __device__ float b2f(unsigned short u) {
  union { float f; unsigned int i; } v; v.i = ((unsigned int)u) << 16; return v.f;
}
static inline __device__ unsigned short f2b(float f) {
  union { float f; unsigned int i; } v; v.f = f;
  unsigned int x = v.i;
  x += 0x7fffu + ((x >> 16) & 1u);   // round-to-nearest-even
  return (unsigned short)(x >> 16);
}

// edge weight: exp(sigmoid(x)) — SAME formula in both agg kernels
static inline __device__ float edgew(float x) {
  float al = 1.f / (1.f + __expf(-x));
  return __expf(al);
}

// async global->LDS, 16B per lane. LDS dest = wave-uniform base + lane*16.
static __device__ __forceinline__ void gld16(const unsigned short* g, unsigned short* l) {
  __builtin_amdgcn_global_load_lds(
      (const __attribute__((address_space(1))) void*)g,
      (__attribute__((address_space(3))) void*)l, 16, 0, 0);
}

// ---- runtime dtype probe ----
__global__ __launch_bounds__(256) void probe_kernel(
    const unsigned int* __restrict__ feat, const unsigned int* __restrict__ eidx,
    int* __restrict__ flags)
{
  int t = threadIdx.x;
  __shared__ int cnt, oddnz;
  if (t == 0) { cnt = 0; oddnz = 0; }
  __syncthreads();
  unsigned int w = feat[t];
  unsigned short lo = (unsigned short)(w & 0xFFFFu);
  int e = (lo >> 7) & 0xFF;
  int plausible = ((lo & 0x7FFF) == 0) || (e >= 0x60 && e <= 0x9F);
  atomicAdd(&cnt, plausible);
  if (t & 1) { if (eidx[t] != 0u) atomicAdd(&oddnz, 1); }
  __syncthreads();
  if (t == 0) { flags[0] = (cnt >= 192) ? 1 : 0; flags[1] = (oddnz == 0) ? 1 : 0; }
}

// ---- radix pass A: per-block slab counts (LDS hist, plain global writes) ----
__global__ __launch_bounds__(256) void cnt_kernel(
    const unsigned int* __restrict__ eidx, int* __restrict__ bcnt,
    int E, const int* __restrict__ flags)
{
  __shared__ int hist[256];
  int t = threadIdx.x;
  hist[t] = 0;
  __syncthreads();
  int e0 = blockIdx.x * PCH;
  const int i64 = flags[1];
  for (int i = t; i < PCH; i += 256) {
    int e = e0 + i; if (e >= E) break;
    int d = i64 ? (int)eidx[2 * ((size_t)E + e)] : (int)eidx[(size_t)E + e];
    atomicAdd(&hist[d >> SHIFT], 1);
  }
  __syncthreads();
  bcnt[blockIdx.x * 256 + t] = hist[t];
}

// ---- radix pass B: bcnt -> within-slab block prefixes; slabOff excl scan ----
__global__ __launch_bounds__(256) void bscan_kernel(
    int* __restrict__ bcnt, int* __restrict__ slabOff, int npb)
{
  __shared__ int wsum[4];
  int t = threadIdx.x, lane = t & 63, wv = t >> 6;
  int run = 0;
  for (int b = 0; b < npb; ++b) {
    int v = bcnt[b * 256 + t];
    bcnt[b * 256 + t] = run;     // within-slab prefix
    run += v;
  }
  int inc = run;
#pragma unroll
  for (int o = 1; o < 64; o <<= 1) {
    int u = __shfl_up(inc, o);
    if (lane >= o) inc += u;
  }
  if (lane == 63) wsum[wv] = inc;
  __syncthreads();
  if (t < 4) {
    int v = wsum[t], s = v;
#pragma unroll
    for (int o = 1; o < 4; o <<= 1) {
      int u = __shfl_up(s, o);
      if (t >= o) s += u;
    }
    wsum[t] = s - v;
  }
  __syncthreads();
  int exc = wsum[wv] + inc - run;
  slabOff[t] = exc;
  if (t == 255) slabOff[256] = exc + run;   // = E
}

// ---- radix pass C: scatter (src,dst) into slab-contiguous part[] ----
__global__ __launch_bounds__(256) void scat_kernel(
    const unsigned int* __restrict__ eidx, const int* __restrict__ bcnt,
    const int* __restrict__ slabOff, uint2* __restrict__ part,
    int E, const int* __restrict__ flags)
{
  __shared__ int cur[256];
  int t = threadIdx.x;
  cur[t] = slabOff[t] + bcnt[blockIdx.x * 256 + t];
  __syncthreads();
  int e0 = blockIdx.x * PCH;
  const int i64 = flags[1];
  for (int i = t; i < PCH; i += 256) {
    int e = e0 + i; if (e >= E) break;
    int s, d;
    if (i64) { s = (int)eidx[2 * (size_t)e]; d = (int)eidx[2 * ((size_t)E + e)]; }
    else     { s = (int)eidx[e];             d = (int)eidx[(size_t)E + e]; }
    int pos = atomicAdd(&cur[d >> SHIFT], 1);
    part[pos] = make_uint2((unsigned)s, (unsigned)d);
  }
}

// ---- radix pass D: per-slab CSR build fully in LDS (deg, scan, fill) ----
__global__ __launch_bounds__(256) void slabcsr_kernel(
    const uint2* __restrict__ part, const int* __restrict__ slabOff,
    int* __restrict__ offs, int* __restrict__ srcP, int N, int nslab)
{
  __shared__ int deg[SLABN];
  __shared__ int wsum[4];
  int sl = blockIdx.x, t = threadIdx.x;
  int n0 = sl << SHIFT;
  int nn = N - n0; if (nn > SLABN) nn = SLABN;
  int s0 = slabOff[sl], s1 = slabOff[sl + 1];
  for (int i = t; i < SLABN; i += 256) deg[i] = 0;
  __syncthreads();
  for (int i = s0 + t; i < s1; i += 256)
    atomicAdd(&deg[(int)part[i].y - n0], 1);
  __syncthreads();
  int bi = t * 2;
  int l0 = deg[bi], l1 = deg[bi + 1];
  int s = l0 + l1;
  int ws = s;
#pragma unroll
  for (int o = 1; o < 64; o <<= 1) {
    int u = __shfl_up(ws, o);
    if ((t & 63) >= o) ws += u;
  }
  if ((t & 63) == 63) wsum[t >> 6] = ws;
  __syncthreads();
  if (t < 4) {
    int v = wsum[t], inc = v;
#pragma unroll
    for (int o = 1; o < 4; o <<= 1) {
      int u = __shfl_up(inc, o);
      if (t >= o) inc += u;
    }
    wsum[t] = inc - v;
  }
  __syncthreads();
  int run = wsum[t >> 6] + (ws - s);   // thread-exclusive base
  deg[bi] = run;
  if (bi < nn) offs[n0 + bi] = s0 + run;
  run += l0;
  deg[bi + 1] = run;
  if (bi + 1 < nn) offs[n0 + bi + 1] = s0 + run;
  __syncthreads();
  for (int i = s0 + t; i < s1; i += 256) {
    uint2 p = part[i];
    int pos = s0 + atomicAdd(&deg[(int)p.y - n0], 1);
    srcP[pos] = (int)p.x;
  }
  if (sl == nslab - 1 && t == 0) offs[N] = s1;
}

static inline __device__ float ldadapt(const void* p, size_t i, int isbf) {
  return isbf ? b2f(((const unsigned short*)p)[i]) : ((const float*)p)[i];
}

// ---- weight prep: W1b, W1tb, W2f, W2b64 ([256][64] bf16, zero-padded K), att ----
__global__ __launch_bounds__(256) void prep_weights(
    const void* __restrict__ W1, const void* __restrict__ W2,
    const void* __restrict__ aS, const void* __restrict__ aD,
    unsigned short* __restrict__ W1b, unsigned short* __restrict__ W1tb,
    float* __restrict__ W2f, unsigned short* __restrict__ W2b64,
    float* __restrict__ atS, float* __restrict__ atD,
    const int* __restrict__ flags)
{
  const int fb = flags[0];
  int i = blockIdx.x * 256 + threadIdx.x;
  if (i < INDIM * HIDD) {               // W1: [512][256]
    int r = i >> 8, c = i & 255;
    float w0 = ldadapt(W1, i, fb);
    unsigned short wb = f2b(w0);
    W1b[i] = wb;                        // Bt for h4: [512 rows][256 k]
    W1tb[c * INDIM + r] = wb;           // Bt for xp1: [256 rows][512 k]
  }
  if (i < HIDD * OUTD) {                // W2: [256][32]
    int r = i >> 5, c = i & 31;
    float w0 = ldadapt(W2, i, fb);
    W2f[i] = w0;
    W2b64[r * 64 + c] = f2b(w0);        // Bt for h3: [256 rows][64 k], upper 32 zero
    W2b64[r * 64 + 32 + c] = 0;
  }
  if (i < HIDD) { atS[i] = ldadapt(aS, i, fb); atD[i] = ldadapt(aD, i, fb); }
}

// =====================================================================
// MFMA NT GEMM, BM=128 x BN=256, BK=64, 512 threads = 8 waves (2x4 of
// 64x64 — per-wave fragment pattern identical to the proven kernel).
// grid.x = Nn/256: for Nn=256 the A-tile is read EXACTLY ONCE (no
// cross-block re-read). T2 swizzle (rule #21 form: linear LDS dest for
// global_load_lds + inverse-swizzled GLOBAL source + swizzled ds_read).
// Single-buffered (48KB LDS, 3 blocks/CU; r14 dbuf was neutral).
// AMODE:   0 = A bf16 ws buffer; 1 = A external: fb ? bf16 : f32 reg-staged
// OUTMODE: 0 = bf16 to Cb; 1 = adaptive (flags[0]) to Out+outOff
// EPI:     0 = none; 1 = ELU before store
// =====================================================================
template<int AMODE, int OUTMODE, int EPI>
__global__ __launch_bounds__(512, 4) void gemm_nt2(
    const void* __restrict__ Av, const unsigned short* __restrict__ Bt,
    unsigned short* __restrict__ Cb, void* __restrict__ Out, size_t outOff,
    const int* __restrict__ flags, int M, int Nn, int K)
{
  __shared__ unsigned short Als[128 * 64];   // 16 KB
  __shared__ unsigned short Bls[256 * 64];   // 32 KB
  const int tid = threadIdx.x, lane = tid & 63, wid = tid >> 6;   // 8 waves
  const int wr = wid >> 2, wc = wid & 3;     // 2x4 wave grid, 64x64 each
  const int rowBase = blockIdx.y * 128, colBase = blockIdx.x * 256;
  const int fb = flags[0];

  const int srow = (lane >> 3), sg = lane & 7;
  const int sgx = sg ^ srow;                 // inverse-swizzled source granule

  f32x4 acc[4][4] = {};

  for (int kt = 0; kt < K; kt += 64) {
    // ---- stage A: 16 chunks (1KB = 8 rows), 2 per wave ----
    if (AMODE == 1 && !fb) {
      const float* Af = (const float*)Av;
#pragma unroll
      for (int i = 0; i < 2; ++i) {
        int row = wid * 16 + i * 8 + srow;
        int gr = rowBase + row; if (gr > M - 1) gr = M - 1;
        const float* sp = Af + (size_t)gr * K + kt + sg * 8;   // linear coalesced
        float4 lo = *(const float4*)sp;
        float4 hi = *(const float4*)(sp + 4);
        union { unsigned short us[8]; int4 v; } cv;
        cv.us[0] = f2b(lo.x); cv.us[1] = f2b(lo.y); cv.us[2] = f2b(lo.z); cv.us[3] = f2b(lo.w);
        cv.us[4] = f2b(hi.x); cv.us[5] = f2b(hi.y); cv.us[6] = f2b(hi.z); cv.us[7] = f2b(hi.w);
        *(int4*)(Als + row * 64 + (sgx << 3)) = cv.v;          // swizzled ds_write
      }
    } else {
      const unsigned short* Ab = (const unsigned short*)Av;
#pragma unroll
      for (int i = 0; i < 2; ++i) {
        int row = wid * 16 + i * 8 + srow;
        int gr = rowBase + row;
        if (AMODE == 1 && gr > M - 1) gr = M - 1;   // external input: clamp
        gld16(Ab + (size_t)gr * K + kt + (sgx << 3), Als + (wid * 2 + i) * 512);
      }
    }
    // ---- stage B: 32 chunks, 4 per wave ----
#pragma unroll
    for (int i = 0; i < 4; ++i) {
      int row = wid * 32 + i * 8 + srow;
      gld16(Bt + (size_t)(colBase + row) * K + kt + (sgx << 3), Bls + (wid * 4 + i) * 512);
    }
    __syncthreads();

    bf16x8 af[4], bfr[4];
#pragma unroll
    for (int ks = 0; ks < 2; ++ks) {
      int gl = ks * 4 + (lane >> 4);
      int gx = gl ^ (lane & 7);        // row&7 == lane&7 for fragment rows
#pragma unroll
      for (int mi = 0; mi < 4; ++mi) {
        int row = wr * 64 + mi * 16 + (lane & 15);
        af[mi] = *(const bf16x8*)(Als + row * 64 + (gx << 3));
      }
#pragma unroll
      for (int ni = 0; ni < 4; ++ni) {
        int row = wc * 64 + ni * 16 + (lane & 15);
        bfr[ni] = *(const bf16x8*)(Bls + row * 64 + (gx << 3));
      }
#pragma unroll
      for (int mi = 0; mi < 4; ++mi)
#pragma unroll
        for (int ni = 0; ni < 4; ++ni)
          acc[mi][ni] = __builtin_amdgcn_mfma_f32_16x16x32_bf16(af[mi], bfr[ni], acc[mi][ni], 0, 0, 0);
    }
    __syncthreads();
  }

  // C/D: col = lane&15, row = (lane>>4)*4 + reg
#pragma unroll
  for (int mi = 0; mi < 4; ++mi) {
    int r0 = rowBase + wr * 64 + mi * 16 + (lane >> 4) * 4;
#pragma unroll
    for (int ni = 0; ni < 4; ++ni) {
      int c = colBase + wc * 64 + ni * 16 + (lane & 15);
#pragma unroll
      for (int v = 0; v < 4; ++v) {
        int r = r0 + v;
        if (r < M) {
          size_t idx = (size_t)r * Nn + c;
          float x = acc[mi][ni][v];
          if (EPI) x = x > 0.f ? x : expm1f(x);
          if (OUTMODE == 0) Cb[idx] = f2b(x);
          else {
            if (fb) ((unsigned short*)Out)[outOff + idx] = f2b(x);
            else    ((float*)Out)[outOff + idx] = x;
          }
        }
      }
    }
  }
}

// ---- a_src / a_dst: one wave per node, dot(xp1_row, att); P is bf16 ----
__global__ __launch_bounds__(256) void rowdots(
    const unsigned short* __restrict__ P, const float* __restrict__ atS,
    const float* __restrict__ atD,
    float* __restrict__ asrc, float* __restrict__ adst, int N)
{
  int wave = threadIdx.x >> 6, lane = threadIdx.x & 63;
  int node = blockIdx.x * 4 + wave;
  if (node >= N) return;
  ushort4 u = *(const ushort4*)(P + (size_t)node * HIDD + lane * 4);
  float4 v = make_float4(b2f(u.x), b2f(u.y), b2f(u.z), b2f(u.w));
  float4 s = *(const float4*)(atS + lane * 4);
  float4 d = *(const float4*)(atD + lane * 4);
  float s1 = v.x * s.x + v.y * s.y + v.z * s.z + v.w * s.w;
  float s2 = v.x * d.x + v.y * d.y + v.z * d.z + v.w * d.w;
#pragma unroll
  for (int off = 32; off; off >>= 1) {
    s1 += __shfl_down(s1, off);
    s2 += __shfl_down(s2, off);
  }
  if (lane == 0) { asrc[node] = s1; adst[node] = s2; }
}

// ---- agg layer 1: wave/node, 16 gathers in flight, denominator in-loop ----
__global__ __launch_bounds__(256) void agg_elu2(
    const unsigned short* __restrict__ xp,
    const float* __restrict__ asrc, const float* __restrict__ adst,
    const int* __restrict__ srcP, const int* __restrict__ offs,
    unsigned short* __restrict__ hout, int N)
{
  __shared__ int   sS[4][64];
  __shared__ float sW[4][64];
  int wid = threadIdx.x >> 6, lane = threadIdx.x & 63;
  int node = blockIdx.x * 4 + wid;
  if (node >= N) return;
  const float ad = adst[node];
  int s0 = offs[node], s1 = offs[node + 1];
  float a0 = 0.f, a1 = 0.f, a2 = 0.f, a3 = 0.f, den = 0.f;
  for (int base = s0; base < s1; base += 64) {
    int cnt = s1 - base; if (cnt > 64) cnt = 64;
    if (lane < cnt) {
      int sv = srcP[base + lane];
      sS[wid][lane] = sv;
      sW[wid][lane] = edgew(asrc[sv] + ad);
    }
    asm volatile("s_waitcnt lgkmcnt(0)" ::: "memory");   // wave-local LDS RAW fence
    int j = 0;
    for (; j + 16 <= cnt; j += 16) {          // 16 gathers in flight
      ushort4 u[16];
#pragma unroll
      for (int q = 0; q < 16; ++q)
        u[q] = *(const ushort4*)(xp + (size_t)sS[wid][j + q] * HIDD + lane * 4);
#pragma unroll
      for (int q = 0; q < 16; ++q) {
        float wv = sW[wid][j + q];
        den += wv;
        a0 += wv * b2f(u[q].x); a1 += wv * b2f(u[q].y);
        a2 += wv * b2f(u[q].z); a3 += wv * b2f(u[q].w);
      }
    }
    for (; j + 8 <= cnt; j += 8) {
      ushort4 u[8];
#pragma unroll
      for (int q = 0; q < 8; ++q)
        u[q] = *(const ushort4*)(xp + (size_t)sS[wid][j + q] * HIDD + lane * 4);
#pragma unroll
      for (int q = 0; q < 8; ++q) {
        float wv = sW[wid][j + q];
        den += wv;
        a0 += wv * b2f(u[q].x); a1 += wv * b2f(u[q].y);
        a2 += wv * b2f(u[q].z); a3 += wv * b2f(u[q].w);
      }
    }
    for (; j < cnt; ++j) {
      int   sv = sS[wid][j];
      float wv = sW[wid][j];
      den += wv;
      ushort4 u = *(const ushort4*)(xp + (size_t)sv * HIDD + lane * 4);
      a0 += wv * b2f(u.x); a1 += wv * b2f(u.y); a2 += wv * b2f(u.z); a3 += wv * b2f(u.w);
    }
  }
  float inv = 1.f / (den + 1e-16f);
  float r0 = a0 * inv, r1 = a1 * inv, r2 = a2 * inv, r3 = a3 * inv;
  r0 = r0 > 0.f ? r0 : expm1f(r0);
  r1 = r1 > 0.f ? r1 : expm1f(r1);
  r2 = r2 > 0.f ? r2 : expm1f(r2);
  r3 = r3 > 0.f ? r3 : expm1f(r3);
  ushort4 o; o.x = f2b(r0); o.y = f2b(r1); o.z = f2b(r2); o.w = f2b(r3);
  *(ushort4*)(hout + (size_t)node * HIDD + lane * 4) = o;
}

// ---- h2 = h1 @ W2 ([N,256]x[256,32]) -> adaptive out + bf16 copy ----
__global__ __launch_bounds__(256) void gemm_h2(
    const unsigned short* __restrict__ H1, const float* __restrict__ W2f,
    void* __restrict__ Out, unsigned short* __restrict__ h2b,
    const int* __restrict__ flags, int M)
{
  const int fb = flags[0];
  __shared__ float Bs[HIDD][33];
  __shared__ float As[8][HIDD];
  int tid = threadIdx.x;
  int tx = tid & 31, ty = tid >> 5;
  int row0 = blockIdx.x * 8;
#pragma unroll
  for (int j = 0; j < 8; ++j) {            // W2 (256x32 f32) via float4
    int idx4 = tid + 256 * j;              // 2048 float4s
    float4 v = *(const float4*)(W2f + idx4 * 4);
    int k = idx4 >> 3, c = (idx4 & 7) * 4;
    Bs[k][c] = v.x; Bs[k][c + 1] = v.y; Bs[k][c + 2] = v.z; Bs[k][c + 3] = v.w;
  }
  {
    int flat = tid * 8;                    // 8 rows x 256 = 2048 bf16, 16B/thread
    int r = flat >> 8, k = flat & 255;
    int gr = row0 + r;
    if (gr < M) {
      ushort4 lo = *(const ushort4*)(H1 + (size_t)gr * HIDD + k);
      ushort4 hi = *(const ushort4*)(H1 + (size_t)gr * HIDD + k + 4);
      As[r][k] = b2f(lo.x); As[r][k + 1] = b2f(lo.y); As[r][k + 2] = b2f(lo.z); As[r][k + 3] = b2f(lo.w);
      As[r][k + 4] = b2f(hi.x); As[r][k + 5] = b2f(hi.y); As[r][k + 6] = b2f(hi.z); As[r][k + 7] = b2f(hi.w);
    } else {
#pragma unroll
      for (int q = 0; q < 8; ++q) As[r][k + q] = 0.f;
    }
  }
  __syncthreads();
  float acc = 0.f;
#pragma unroll 8
  for (int k = 0; k < HIDD; ++k) acc += As[ty][k] * Bs[k][tx];
  int row = row0 + ty;
  if (row < M) {
    size_t idx = (size_t)row * OUTD + tx;
    if (fb) ((unsigned short*)Out)[idx] = f2b(acc);
    else    ((float*)Out)[idx] = acc;
    h2b[idx] = f2b(acc);
  }
}

// ---- agg layer 2 on h2 [N,32] bf16 -> g2pad [N][64], w recomputed inline ----
__global__ __launch_bounds__(256) void agg_small(
    const unsigned short* __restrict__ h2b,
    const float* __restrict__ asrc, const float* __restrict__ adst,
    const int* __restrict__ srcP, const int* __restrict__ offs,
    unsigned short* __restrict__ g2pad, int N)
{
  int wid = threadIdx.x >> 6, lane = threadIdx.x & 63;
  int node = blockIdx.x * 4 + wid;
  if (node >= N) return;
  int grp = lane >> 4, cl = lane & 15;
  const float ad = adst[node];
  int s0 = offs[node], s1 = offs[node + 1];
  float a0 = 0.f, a1 = 0.f, den = 0.f;
  for (int e = s0 + grp; e < s1; e += 4) {
    int   sv = srcP[e];          // uniform across the 16-lane group (broadcast)
    float wv = edgew(asrc[sv] + ad);
    den += wv;
    ushort2 u = *(const ushort2*)(h2b + (size_t)sv * OUTD + cl * 2);
    a0 += wv * b2f(u.x);
    a1 += wv * b2f(u.y);
  }
  a0 += __shfl_xor(a0, 16); a0 += __shfl_xor(a0, 32);
  a1 += __shfl_xor(a1, 16); a1 += __shfl_xor(a1, 32);
  den += __shfl_xor(den, 16); den += __shfl_xor(den, 32);
  if (grp == 0) {
    float inv = 1.f / (den + 1e-16f);
    ushort2 o; o.x = f2b(a0 * inv); o.y = f2b(a1 * inv);
    *(ushort2*)(g2pad + (size_t)node * 64 + cl * 2) = o;
  } else if (grp == 1) {
    *(ushort2*)(g2pad + (size_t)node * 64 + 32 + cl * 2) = make_ushort2(0, 0);  // K-pad
  }
}

extern "C" void kernel_launch(void* const* d_in, const int* in_sizes, int n_in,
                              void* d_out, int out_size, void* d_ws, size_t ws_size,
                              hipStream_t stream)
{
  const void*         feat = d_in[0];
  const unsigned int* eidx = (const unsigned int*)d_in[1];
  const void*         W1   = d_in[2];
  const void*         W2   = d_in[3];
  const void*         aS   = d_in[4];
  const void*         aD   = d_in[5];

  const int N = in_sizes[0] / INDIM;
  const int E = in_sizes[1] / 2;
  const int M_pad = ((N + 127) / 128) * 128;
  const int nslab = (N + SLABN - 1) / SLABN;   // 196 for N=100000; must be <= 256
  const int npb = (E + PCH - 1) / PCH;

  char* w = (char*)d_ws;
  auto alloc = [&](size_t bytes) -> char* {
    char* p = w; w += (bytes + 255) & ~(size_t)255; return p;
  };
  unsigned short* H     = (unsigned short*)alloc((size_t)M_pad * HIDD * 2);  // h1 / h3
  unsigned short* P     = (unsigned short*)alloc((size_t)M_pad * HIDD * 2);  // xp1
  unsigned short* h2b   = (unsigned short*)alloc((size_t)N * OUTD * 2);      // h2 bf16
  unsigned short* g2pad = (unsigned short*)alloc((size_t)M_pad * 64 * 2);    // agg(h2), K-padded
  float* asrc = (float*)alloc((size_t)N * 4);
  float* adst = (float*)alloc((size_t)N * 4);
  int*   srcP = (int*)alloc((size_t)E * 4);     // CSR-ordered edge src
  uint2* part = (uint2*)alloc((size_t)E * 8);   // slab-partitioned (src,dst)
  int*   offs = (int*)alloc((size_t)(N + 1) * 4);
  int*   bcnt = (int*)alloc((size_t)npb * 256 * 4);
  int*   slabOff = (int*)alloc(257 * 4);
  unsigned short* W1b   = (unsigned short*)alloc((size_t)INDIM * HIDD * 2); // [512][256]
  unsigned short* W1tb  = (unsigned short*)alloc((size_t)INDIM * HIDD * 2); // [256][512]
  unsigned short* W2b64 = (unsigned short*)alloc((size_t)HIDD * 64 * 2);    // [256][64]
  float* W2f  = (float*)alloc((size_t)HIDD * OUTD * 4);
  float* atS  = (float*)alloc((size_t)HIDD * 4);
  float* atD  = (float*)alloc((size_t)HIDD * 4);
  int*   flags = (int*)alloc(64);

  probe_kernel<<<1, 256, 0, stream>>>((const unsigned int*)feat, eidx, flags);

  // CSR build: radix by dst-slab (512-node slabs), slab-local CSR in LDS
  cnt_kernel<<<npb, 256, 0, stream>>>(eidx, bcnt, E, flags);
  bscan_kernel<<<1, 256, 0, stream>>>(bcnt, slabOff, npb);
  scat_kernel<<<npb, 256, 0, stream>>>(eidx, bcnt, slabOff, part, E, flags);
  slabcsr_kernel<<<nslab, 256, 0, stream>>>(part, slabOff, offs, srcP, N, nslab);

  prep_weights<<<512, 256, 0, stream>>>(W1, W2, aS, aD, W1b, W1tb, W2f, W2b64, atS, atD, flags);

  const int mb = (N + 127) / 128;

  // xp1 = feat @ W1 : BN=256 covers all of HIDD -> A read exactly once
  gemm_nt2<1, 0, 0><<<dim3(1, mb), 512, 0, stream>>>(
      feat, W1tb, P, nullptr, 0, flags, N, HIDD, INDIM);

  rowdots<<<(N + 3) / 4, 256, 0, stream>>>(P, atS, atD, asrc, adst, N);

  // GAT layer 1: h1 = elu(agg(xp1)/denom)
  agg_elu2<<<(N + 3) / 4, 256, 0, stream>>>(P, asrc, adst, srcP, offs, H, N);

  // h2 = h1 @ W2 -> output 0 (+ bf16 copy for layer-2 agg)
  gemm_h2<<<(N + 7) / 8, 256, 0, stream>>>(H, W2f, d_out, h2b, flags, N);

  // GAT layer 2, commuted: g2 = agg(h2) [N,32->64pad]
  agg_small<<<(N + 3) / 4, 256, 0, stream>>>(h2b, asrc, adst, srcP, offs, g2pad, N);

  // h3 = elu(g2 @ W2^T) via MFMA GEMM (single K-step)
  gemm_nt2<0, 0, 1><<<dim3(1, mb), 512, 0, stream>>>(
      g2pad, W2b64, H, nullptr, 0, flags, N, HIDD, 64);

  // h4 = h3 @ W1^T -> output 1 (adaptive)
  gemm_nt2<0, 1, 0><<<dim3(2, mb), 512, 0, stream>>>(
      H, W1b, nullptr, d_out, (size_t)N * OUTD, flags, N, INDIM, HIDD);
}